// Round 13
// baseline (400.472 us; speedup 1.0000x reference)
//
#include <hip/hip_runtime.h>

#define NB 16
#define CDIM 512
#define NHEAD 8
#define DHEAD 64
#define NSEQ 4096
#define O3 1536

typedef __attribute__((ext_vector_type(8))) short short8;
typedef __attribute__((ext_vector_type(4))) float f32x4;
typedef __attribute__((ext_vector_type(4))) unsigned u32x4;
typedef __attribute__((ext_vector_type(2))) unsigned u32x2;
typedef __attribute__((ext_vector_type(4))) float fvec4;

__device__ __forceinline__ float bf2f(unsigned short u){
  union { unsigned u; float f; } v; v.u = ((unsigned)u) << 16; return v.f;
}
__device__ __forceinline__ unsigned short f2bf(float f){
  union { float f; unsigned u; } v; v.f = f;
  unsigned r = v.u + 0x7fffu + ((v.u >> 16) & 1u);
  return (unsigned short)(r >> 16);
}
__device__ __forceinline__ unsigned pack2(float a, float b){
  return (unsigned)f2bf(a) | ((unsigned)f2bf(b) << 16);
}
__device__ __forceinline__ void gld_lds16(const void* g, void* l){
  __builtin_amdgcn_global_load_lds(
      (const __attribute__((address_space(1))) unsigned*)g,
      (__attribute__((address_space(3))) unsigned*)l, 16, 0, 0);
}

// ---- w_qkv f32 -> bf16 ----
__global__ __launch_bounds__(256) void k_conv_w(const float* __restrict__ w,
                                                unsigned short* __restrict__ o){
  int i = (blockIdx.x*256 + threadIdx.x)*4;
  fvec4 v = *(const fvec4*)(w + i);
  u32x2 p; p[0] = pack2(v[0], v[1]); p[1] = pack2(v[2], v[3]);
  *(u32x2*)(o + i) = p;
}

// ---- x [b][c][n] f32 -> xT [b][n][c] bf16; 16B reads, 16B writes ----
__global__ __launch_bounds__(256) void k_transpose_x(const float* __restrict__ x,
                                                     unsigned short* __restrict__ xT){
  __shared__ unsigned short tile[64][65];
  int b = blockIdx.z, c0 = blockIdx.y*64, n0 = blockIdx.x*64;
  int t = threadIdx.x;
  const float* xb = x + ((size_t)b*CDIM + c0)*NSEQ + n0;
  #pragma unroll
  for (int i=0;i<4;i++){
    int idx = t + i*256;
    int r = idx>>4, c4 = (idx&15)*4;
    fvec4 v = *(const fvec4*)(xb + (size_t)r*NSEQ + c4);
    tile[r][c4]   = f2bf(v[0]);
    tile[r][c4+1] = f2bf(v[1]);
    tile[r][c4+2] = f2bf(v[2]);
    tile[r][c4+3] = f2bf(v[3]);
  }
  __syncthreads();
  unsigned short* ob = xT + ((size_t)b*NSEQ + n0)*CDIM + c0;
  #pragma unroll
  for (int i=0;i<2;i++){
    int chunk = t + i*256;
    int r = chunk>>3, c8 = (chunk&7)*8;
    u32x4 p;
    #pragma unroll
    for (int k=0;k<4;k++)
      p[k] = (unsigned)tile[c8+2*k][r] | ((unsigned)tile[c8+2*k+1][r] << 16);
    *(u32x4*)(ob + (size_t)r*CDIM + c8) = p;
  }
}

// ---- k GEMM: r6 BK=64 split-half body, uniform exp epilogue -> KV rows 0-511 ----
__global__ __launch_bounds__(256) void k_gemm_k(const unsigned short* __restrict__ A,
                                                const unsigned short* __restrict__ Bt,
                                                unsigned short* __restrict__ KV){
  __shared__ unsigned short As[2][128*32];
  __shared__ unsigned short Bs[2][128*32];
  int b = blockIdx.z;
  int n0 = blockIdx.x*128, o0 = blockIdx.y*128;
  const unsigned short* Bb = Bt + (size_t)b*NSEQ*CDIM;
  unsigned short* Cb = KV + (size_t)b*1024*NSEQ;
  int t = threadIdx.x, w = t>>6, l = t&63;
  int lr = l&15, kq = (l>>4)*8;
  int wr = (w>>1)*64, wc = (w&1)*64;
  f32x4 acc[4][4];
  #pragma unroll
  for (int mi=0;mi<4;mi++)
    #pragma unroll
    for (int ni=0;ni<4;ni++) acc[mi][ni] = (f32x4){0.f,0.f,0.f,0.f};
  for (int k0=0;k0<CDIM;k0+=64){
    #pragma unroll
    for (int h=0;h<2;++h){
      #pragma unroll
      for (int it=0;it<2;++it){
        int chunk = it*256 + t;
        int row = chunk>>2, kc = (chunk&3)*8;
        gld_lds16(A  + (size_t)(o0+row)*CDIM + k0 + h*32 + kc, (char*)As[h] + (size_t)chunk*16);
        gld_lds16(Bb + (size_t)(n0+row)*CDIM + k0 + h*32 + kc, (char*)Bs[h] + (size_t)chunk*16);
      }
    }
    __syncthreads();
    #pragma unroll
    for (int h=0;h<2;++h){
      short8 af[4], bfv[4];
      #pragma unroll
      for (int mi=0;mi<4;mi++) af[mi]  = *(const short8*)&As[h][(wr + mi*16 + lr)*32 + kq];
      #pragma unroll
      for (int ni=0;ni<4;ni++) bfv[ni] = *(const short8*)&Bs[h][(wc + ni*16 + lr)*32 + kq];
      #pragma unroll
      for (int mi=0;mi<4;mi++)
        #pragma unroll
        for (int ni=0;ni<4;ni++)
          acc[mi][ni] = __builtin_amdgcn_mfma_f32_16x16x32_bf16(af[mi], bfv[ni], acc[mi][ni], 0, 0, 0);
    }
    __syncthreads();
  }
  #pragma unroll
  for (int mi=0;mi<4;mi++)
    #pragma unroll
    for (int ni=0;ni<4;ni++)
      #pragma unroll
      for (int r=0;r<4;r++){
        int row = o0 + wr + mi*16 + (l>>4)*4 + r;
        int col = n0 + wc + ni*16 + lr;
        Cb[(size_t)row*NSEQ + col] = f2bf(__expf(acc[mi][ni][r]));
      }
}

// ---- v GEMM: r6 BK=64 split-half body, plain epilogue -> KV rows 512-1023 ----
__global__ __launch_bounds__(256) void k_gemm_v(const unsigned short* __restrict__ A,
                                                const unsigned short* __restrict__ Bt,
                                                unsigned short* __restrict__ KV){
  __shared__ unsigned short As[2][128*32];
  __shared__ unsigned short Bs[2][128*32];
  int b = blockIdx.z;
  int n0 = blockIdx.x*128, o0 = blockIdx.y*128;
  const unsigned short* Bb = Bt + (size_t)b*NSEQ*CDIM;
  unsigned short* Cb = KV + (size_t)b*1024*NSEQ + (size_t)512*NSEQ;
  int t = threadIdx.x, w = t>>6, l = t&63;
  int lr = l&15, kq = (l>>4)*8;
  int wr = (w>>1)*64, wc = (w&1)*64;
  f32x4 acc[4][4];
  #pragma unroll
  for (int mi=0;mi<4;mi++)
    #pragma unroll
    for (int ni=0;ni<4;ni++) acc[mi][ni] = (f32x4){0.f,0.f,0.f,0.f};
  for (int k0=0;k0<CDIM;k0+=64){
    #pragma unroll
    for (int h=0;h<2;++h){
      #pragma unroll
      for (int it=0;it<2;++it){
        int chunk = it*256 + t;
        int row = chunk>>2, kc = (chunk&3)*8;
        gld_lds16(A  + (size_t)(o0+row)*CDIM + k0 + h*32 + kc, (char*)As[h] + (size_t)chunk*16);
        gld_lds16(Bb + (size_t)(n0+row)*CDIM + k0 + h*32 + kc, (char*)Bs[h] + (size_t)chunk*16);
      }
    }
    __syncthreads();
    #pragma unroll
    for (int h=0;h<2;++h){
      short8 af[4], bfv[4];
      #pragma unroll
      for (int mi=0;mi<4;mi++) af[mi]  = *(const short8*)&As[h][(wr + mi*16 + lr)*32 + kq];
      #pragma unroll
      for (int ni=0;ni<4;ni++) bfv[ni] = *(const short8*)&Bs[h][(wc + ni*16 + lr)*32 + kq];
      #pragma unroll
      for (int mi=0;mi<4;mi++)
        #pragma unroll
        for (int ni=0;ni<4;ni++)
          acc[mi][ni] = __builtin_amdgcn_mfma_f32_16x16x32_bf16(af[mi], bfv[ni], acc[mi][ni], 0, 0, 0);
    }
    __syncthreads();
  }
  #pragma unroll
  for (int mi=0;mi<4;mi++)
    #pragma unroll
    for (int ni=0;ni<4;ni++)
      #pragma unroll
      for (int r=0;r<4;r++){
        int row = o0 + wr + mi*16 + (l>>4)*4 + r;
        int col = n0 + wc + ni*16 + lr;
        Cb[(size_t)row*NSEQ + col] = f2bf(acc[mi][ni][r]);
      }
}

// ---- q GEMM (r6 BK=64 split halves, inline staging) + in-reg softmax ----
#define TS 136
__global__ __launch_bounds__(256) void k_gemm_q(const unsigned short* __restrict__ A,
                                                const unsigned short* __restrict__ Bt,
                                                unsigned short* __restrict__ qsmT){
  __shared__ unsigned short smem[128*128];   // 32 KB: 4x 128x32 halves; epilogue tile aliases
  int b = blockIdx.z;
  int n0 = blockIdx.x*128, o0 = blockIdx.y*128;
  const unsigned short* Bb = Bt + (size_t)b*NSEQ*CDIM;
  int t = threadIdx.x, w = t>>6, l = t&63;
  int lr = l&15, kq = (l>>4)*8;
  int wr = (w>>1)*64, wc = (w&1)*64;
  f32x4 acc[4][4];
  #pragma unroll
  for (int mi=0;mi<4;mi++)
    #pragma unroll
    for (int ni=0;ni<4;ni++) acc[mi][ni] = (f32x4){0.f,0.f,0.f,0.f};
  for (int k0=0;k0<CDIM;k0+=64){
    #pragma unroll
    for (int h=0;h<2;++h){
      unsigned short* Ash = smem + h*4096;
      unsigned short* Bsh = smem + 8192 + h*4096;
      #pragma unroll
      for (int it=0;it<2;++it){
        int chunk = it*256 + t;
        int row = chunk>>2, kc = (chunk&3)*8;
        gld_lds16(A  + (size_t)(o0+row)*CDIM + k0 + h*32 + kc, (char*)Ash + (size_t)chunk*16);
        gld_lds16(Bb + (size_t)(n0+row)*CDIM + k0 + h*32 + kc, (char*)Bsh + (size_t)chunk*16);
      }
    }
    __syncthreads();
    #pragma unroll
    for (int h=0;h<2;++h){
      const unsigned short* Ash = smem + h*4096;
      const unsigned short* Bsh = smem + 8192 + h*4096;
      short8 af[4], bfv[4];
      #pragma unroll
      for (int mi=0;mi<4;mi++) af[mi]  = *(const short8*)&Ash[(wr + mi*16 + lr)*32 + kq];
      #pragma unroll
      for (int ni=0;ni<4;ni++) bfv[ni] = *(const short8*)&Bsh[(wc + ni*16 + lr)*32 + kq];
      #pragma unroll
      for (int mi=0;mi<4;mi++)
        #pragma unroll
        for (int ni=0;ni<4;ni++)
          acc[mi][ni] = __builtin_amdgcn_mfma_f32_16x16x32_bf16(af[mi], bfv[ni], acc[mi][ni], 0, 0, 0);
    }
    __syncthreads();
  }
  // in-register softmax over d (wave's 64 rows = one head) per column
  unsigned pk[4][4][2];
  #pragma unroll
  for (int ni=0;ni<4;ni++){
    float mx = -1e30f;
    #pragma unroll
    for (int mi=0;mi<4;mi++)
      #pragma unroll
      for (int r=0;r<4;r++) mx = fmaxf(mx, acc[mi][ni][r]);
    mx = fmaxf(mx, __shfl_xor(mx, 16, 64));
    mx = fmaxf(mx, __shfl_xor(mx, 32, 64));
    float s = 0.f;
    #pragma unroll
    for (int mi=0;mi<4;mi++)
      #pragma unroll
      for (int r=0;r<4;r++){
        float p = __expf(acc[mi][ni][r] - mx);
        acc[mi][ni][r] = p; s += p;
      }
    s += __shfl_xor(s, 16, 64);
    s += __shfl_xor(s, 32, 64);
    float inv = 0.125f / s;
    #pragma unroll
    for (int mi=0;mi<4;mi++){
      pk[mi][ni][0] = pack2(acc[mi][ni][0]*inv, acc[mi][ni][1]*inv);
      pk[mi][ni][1] = pack2(acc[mi][ni][2]*inv, acc[mi][ni][3]*inv);
    }
  }
  #pragma unroll
  for (int ck=0;ck<2;++ck){
    if ((w&1) == ck){
      #pragma unroll
      for (int mi=0;mi<4;mi++)
        #pragma unroll
        for (int ni=0;ni<4;ni++){
          int idx = (ni*16 + lr)*TS + wr + mi*16 + (l>>4)*4;
          u32x2 p; p[0] = pk[mi][ni][0]; p[1] = pk[mi][ni][1];
          *(u32x2*)&smem[idx] = p;
        }
    }
    __syncthreads();
    int col = t>>2, rs = (t&3)*32;
    unsigned short* dst = qsmT + ((size_t)b*NSEQ + n0 + ck*64 + col)*CDIM + o0 + rs;
    #pragma unroll
    for (int j=0;j<4;++j)
      *(u32x4*)(dst + j*8) = *(const u32x4*)&smem[col*TS + rs + j*8];
    __syncthreads();
  }
}

// ---- partial context over n-chunk; k already holds bf16(exp(k)) ----
__global__ __launch_bounds__(256) void k_context(const unsigned short* __restrict__ KV,
                                                 float* __restrict__ ctx4,
                                                 float* __restrict__ sump){
  __shared__ unsigned short Vs[64*64];
  int m = blockIdx.x, b = blockIdx.y, ch = blockIdx.z;
  int t = threadIdx.x, w = t>>6, l = t&63;
  int lr = l&15, kq = (l>>4)*8;
  const unsigned short* kbase = KV + ((size_t)b*1024 + m*64)*NSEQ;
  const unsigned short* vbase = KV + ((size_t)b*1024 + 512 + m*64)*NSEQ;
  int irow = w*16 + lr;
  int sub = l>>4;
  int nbeg = ch*1024;
  float rsum = 0.f;
  f32x4 acc[4];
  #pragma unroll
  for (int jf=0;jf<4;++jf) acc[jf] = (f32x4){0.f,0.f,0.f,0.f};
  for (int n0=nbeg;n0<nbeg+1024;n0+=64){
    #pragma unroll
    for (int it=0;it<2;++it){
      int chunk = it*256 + t;
      int row = chunk>>3, kc = (chunk&7)*8;
      gld_lds16(vbase + (size_t)row*NSEQ + n0 + kc, (char*)Vs + (size_t)chunk*16);
    }
    __syncthreads();
    #pragma unroll
    for (int kk=0;kk<2;++kk){
      u32x4 kraw = *(const u32x4*)(kbase + (size_t)irow*NSEQ + n0 + kk*32 + kq);
      short8 af = *(const short8*)&kraw;        // bit-identical: values are exp(k) bf16
      #pragma unroll
      for (int c=0;c<4;++c){
        unsigned u = kraw[c];
        rsum += bf2f((unsigned short)u) + bf2f((unsigned short)(u>>16));
      }
      #pragma unroll
      for (int jf=0;jf<4;++jf){
        short8 bv = *(const short8*)&Vs[(jf*16+lr)*64 + kk*32 + kq];
        acc[jf] = __builtin_amdgcn_mfma_f32_16x16x32_bf16(af, bv, acc[jf], 0, 0, 0);
      }
    }
    __syncthreads();
  }
  rsum += __shfl_xor(rsum, 16, 64);
  rsum += __shfl_xor(rsum, 32, 64);
  size_t sbase = (((size_t)ch*NB + b)*NHEAD + m)*64;
  if (sub == 0) sump[sbase + irow] = rsum;
  float* cb = ctx4 + (((size_t)ch*NB + b)*NHEAD + m)*4096;
  #pragma unroll
  for (int jf=0;jf<4;++jf)
    #pragma unroll
    for (int r=0;r<4;++r){
      int i = w*16 + (l>>4)*4 + r;
      int j = jf*16 + lr;
      cb[i*64 + j] = acc[jf][r];
    }
}

// ---- W_eff: plain-sum merge of 4 chunk-partials, then fold w_out ----
__global__ __launch_bounds__(256) void k_weff(const float* __restrict__ ctx4,
                                              const float* __restrict__ sump,
                                              const float* __restrict__ wout,
                                              unsigned short* __restrict__ weff){
  __shared__ float cs[64][65];
  __shared__ float invZ[64];
  int m = blockIdx.x, b = blockIdx.y, z = blockIdx.z;
  int t = threadIdx.x, w = t>>6, l = t&63;
  const size_t chs = (size_t)NB*NHEAD*4096;
  const size_t sts = (size_t)NB*NHEAD*64;
  size_t sb = ((size_t)b*NHEAD + m)*64;
  if (t < 64){
    float Z = sump[sb + t] + sump[sb + sts + t]
            + sump[sb + 2*sts + t] + sump[sb + 3*sts + t];
    invZ[t] = 1.f/Z;
  }
  __syncthreads();
  const float* cb = ctx4 + ((size_t)b*NHEAD + m)*4096;
  for (int idx=t; idx<4096; idx+=256){
    int i = idx>>6;
    cs[i][idx&63] = (cb[idx] + cb[idx+chs] + cb[idx+2*chs] + cb[idx+3*chs]) * invZ[i];
  }
  __syncthreads();
  for (int oo=0;oo<32;++oo){
    int o = z*128 + w*32 + oo;
    float acc = 0.f;
    #pragma unroll
    for (int j=0;j<64;++j) acc += wout[(size_t)o*CDIM + m*64 + j] * cs[l][j];
    weff[((size_t)b*CDIM + o)*CDIM + m*64 + l] = f2bf(acc);
  }
}

// ---- fused final GEMM + bias + channel-LN: 512(o) x 64(n) per block ----
// n-tile 64: acc[4][4]=64 VGPR/thread -> 2 blocks/CU (was 1 at n=128).
__global__ __launch_bounds__(512) void k_out_ln(const unsigned short* __restrict__ Weff,
                                                const unsigned short* __restrict__ QT,
                                                const float* __restrict__ bias,
                                                const float* __restrict__ g,
                                                float* __restrict__ out){
  __shared__ unsigned short As[512*32];   // 32 KB
  __shared__ unsigned short Bs[64*32];    //  4 KB
  __shared__ float lnS[64], lnS2[64];
  int b = blockIdx.y, n0 = blockIdx.x*64;
  const unsigned short* Ab = Weff + (size_t)b*CDIM*CDIM;
  const unsigned short* Bb = QT + ((size_t)b*NSEQ + n0)*CDIM;
  int t = threadIdx.x, w = t>>6, l = t&63;
  int lr = l&15, kq = (l>>4)*8;
  f32x4 acc[4][4];
  #pragma unroll
  for (int mi=0;mi<4;mi++)
    #pragma unroll
    for (int ni=0;ni<4;ni++) acc[mi][ni] = (f32x4){0.f,0.f,0.f,0.f};
  for (int k0=0;k0<CDIM;k0+=32){
    #pragma unroll
    for (int it=0;it<4;++it){
      int chunk = it*512 + t;                     // 2048 chunks = As 32 KB
      int row = chunk>>2, kc = (chunk&3)*8;
      gld_lds16(Ab + (size_t)row*CDIM + k0 + kc, (char*)As + (size_t)chunk*16);
    }
    if (t < 256){                                  // 256 chunks = Bs 4 KB (exact)
      int row = t>>2, kc = (t&3)*8;
      gld_lds16(Bb + (size_t)row*CDIM + k0 + kc, (char*)Bs + (size_t)t*16);
    }
    __syncthreads();
    short8 af[4], bfv[4];
    #pragma unroll
    for (int mi=0;mi<4;mi++) af[mi]  = *(const short8*)&As[(w*64 + mi*16 + lr)*32 + kq];
    #pragma unroll
    for (int ni=0;ni<4;ni++) bfv[ni] = *(const short8*)&Bs[(ni*16 + lr)*32 + kq];
    #pragma unroll
    for (int mi=0;mi<4;mi++)
      #pragma unroll
      for (int ni=0;ni<4;ni++)
        acc[mi][ni] = __builtin_amdgcn_mfma_f32_16x16x32_bf16(af[mi], bfv[ni], acc[mi][ni], 0, 0, 0);
    __syncthreads();
  }
  if (t < 64){ lnS[t] = 0.f; lnS2[t] = 0.f; }
  __syncthreads();
  float ps[4], ps2[4];
  #pragma unroll
  for (int ni=0;ni<4;ni++){ ps[ni]=0.f; ps2[ni]=0.f; }
  #pragma unroll
  for (int mi=0;mi<4;mi++)
    #pragma unroll
    for (int r=0;r<4;r++){
      int row = w*64 + mi*16 + (l>>4)*4 + r;
      float bb = bias[row];
      #pragma unroll
      for (int ni=0;ni<4;ni++){
        float v = acc[mi][ni][r] + bb;
        acc[mi][ni][r] = v;
        ps[ni] += v; ps2[ni] += v*v;
      }
    }
  #pragma unroll
  for (int ni=0;ni<4;ni++){
    ps[ni]  += __shfl_xor(ps[ni], 16, 64);  ps[ni]  += __shfl_xor(ps[ni], 32, 64);
    ps2[ni] += __shfl_xor(ps2[ni], 16, 64); ps2[ni] += __shfl_xor(ps2[ni], 32, 64);
  }
  if ((l>>4) == 0){
    #pragma unroll
    for (int ni=0;ni<4;ni++){
      atomicAdd(&lnS[ni*16+lr],  ps[ni]);
      atomicAdd(&lnS2[ni*16+lr], ps2[ni]);
    }
  }
  __syncthreads();
  if (t < 64){
    float mean = lnS[t]*(1.f/512.f);
    float var  = lnS2[t]*(1.f/512.f) - mean*mean;
    lnS[t] = mean; lnS2[t] = rsqrtf(var + 1e-5f);
  }
  __syncthreads();
  float* ob = out + (size_t)b*CDIM*NSEQ + n0;
  #pragma unroll
  for (int ni=0;ni<4;ni++){
    int col = ni*16 + lr;
    float mean = lnS[col], rstd = lnS2[col];
    #pragma unroll
    for (int mi=0;mi<4;mi++)
      #pragma unroll
      for (int r=0;r<4;r++){
        int row = w*64 + mi*16 + (l>>4)*4 + r;
        ob[(size_t)row*NSEQ + col] = (acc[mi][ni][r] - mean)*rstd*g[row];
      }
  }
}

extern "C" void kernel_launch(void* const* d_in, const int* in_sizes, int n_in,
                              void* d_out, int out_size, void* d_ws, size_t ws_size,
                              hipStream_t stream){
  const float* x     = (const float*)d_in[0];
  const float* w_qkv = (const float*)d_in[1];
  const float* w_out = (const float*)d_in[2];
  const float* b_out = (const float*)d_in[3];
  const float* g_out = (const float*)d_in[4];
  float* out = (float*)d_out;
  char* ws = (char*)d_ws;

  size_t off = 0;
  unsigned short* wq_bf = (unsigned short*)(ws + off); off += (size_t)O3*CDIM*2;          // 1.5 MB
  char* xT_region = ws + off;                          off += (size_t)NB*NSEQ*CDIM*2;     // 67 MB
  unsigned short* qkv_kv = (unsigned short*)(ws + off); off += (size_t)NB*1024*NSEQ*2;    // 134 MB
  unsigned short* qsmT   = (unsigned short*)(ws + off); off += (size_t)NB*NSEQ*CDIM*2;    // 67 MB
  if (off > ws_size) return;
  unsigned short* xT = (unsigned short*)xT_region;
  // aliases into xT region (xT dead after both GEMMs):
  float* sump = (float*)(xT_region);                        // 128 KB
  float* ctx4 = (float*)(xT_region + (1<<20));              // 8 MB (4 chunks)
  unsigned short* weff = (unsigned short*)(xT_region + (16<<20)); // 8.4 MB

  k_conv_w     <<<O3*CDIM/1024, 256, 0, stream>>>(w_qkv, wq_bf);
  k_transpose_x<<<dim3(NSEQ/64, CDIM/64, NB), 256, 0, stream>>>(x, xT);
  k_gemm_k     <<<dim3(NSEQ/128, 4, NB), 256, 0, stream>>>(wq_bf + (size_t)512*CDIM, xT, qkv_kv);
  k_gemm_v     <<<dim3(NSEQ/128, 4, NB), 256, 0, stream>>>(wq_bf + (size_t)1024*CDIM, xT, qkv_kv);
  k_gemm_q     <<<dim3(NSEQ/128, 4, NB), 256, 0, stream>>>(wq_bf, xT, qsmT);
  k_context    <<<dim3(NHEAD, NB, 4), 256, 0, stream>>>(qkv_kv, ctx4, sump);
  k_weff       <<<dim3(NHEAD, NB, 4), 256, 0, stream>>>(ctx4, sump, w_out, weff);
  k_out_ln     <<<dim3(NSEQ/64, NB), 512, 0, stream>>>(weff, qsmT, b_out, g_out, out);
}

// Round 14
// 366.077 us; speedup vs baseline: 1.0940x; 1.0940x over previous
//
#include <hip/hip_runtime.h>

#define NB 16
#define CDIM 512
#define NHEAD 8
#define DHEAD 64
#define NSEQ 4096
#define O3 1536

typedef __attribute__((ext_vector_type(8))) short short8;
typedef __attribute__((ext_vector_type(4))) float f32x4;
typedef __attribute__((ext_vector_type(4))) unsigned u32x4;
typedef __attribute__((ext_vector_type(2))) unsigned u32x2;
typedef __attribute__((ext_vector_type(4))) float fvec4;

__device__ __forceinline__ float bf2f(unsigned short u){
  union { unsigned u; float f; } v; v.u = ((unsigned)u) << 16; return v.f;
}
__device__ __forceinline__ unsigned short f2bf(float f){
  union { float f; unsigned u; } v; v.f = f;
  unsigned r = v.u + 0x7fffu + ((v.u >> 16) & 1u);
  return (unsigned short)(r >> 16);
}
__device__ __forceinline__ unsigned pack2(float a, float b){
  return (unsigned)f2bf(a) | ((unsigned)f2bf(b) << 16);
}
__device__ __forceinline__ void gld_lds16(const void* g, void* l){
  __builtin_amdgcn_global_load_lds(
      (const __attribute__((address_space(1))) unsigned*)g,
      (__attribute__((address_space(3))) unsigned*)l, 16, 0, 0);
}

// ---- w_qkv f32 -> bf16 ----
__global__ __launch_bounds__(256) void k_conv_w(const float* __restrict__ w,
                                                unsigned short* __restrict__ o){
  int i = (blockIdx.x*256 + threadIdx.x)*4;
  fvec4 v = *(const fvec4*)(w + i);
  u32x2 p; p[0] = pack2(v[0], v[1]); p[1] = pack2(v[2], v[3]);
  *(u32x2*)(o + i) = p;
}

// ---- x [b][c][n] f32 -> xT [b][n][c] bf16; 16B reads, 16B writes ----
__global__ __launch_bounds__(256) void k_transpose_x(const float* __restrict__ x,
                                                     unsigned short* __restrict__ xT){
  __shared__ unsigned short tile[64][65];
  int b = blockIdx.z, c0 = blockIdx.y*64, n0 = blockIdx.x*64;
  int t = threadIdx.x;
  const float* xb = x + ((size_t)b*CDIM + c0)*NSEQ + n0;
  #pragma unroll
  for (int i=0;i<4;i++){
    int idx = t + i*256;
    int r = idx>>4, c4 = (idx&15)*4;
    fvec4 v = *(const fvec4*)(xb + (size_t)r*NSEQ + c4);
    tile[r][c4]   = f2bf(v[0]);
    tile[r][c4+1] = f2bf(v[1]);
    tile[r][c4+2] = f2bf(v[2]);
    tile[r][c4+3] = f2bf(v[3]);
  }
  __syncthreads();
  unsigned short* ob = xT + ((size_t)b*NSEQ + n0)*CDIM + c0;
  #pragma unroll
  for (int i=0;i<2;i++){
    int chunk = t + i*256;
    int r = chunk>>3, c8 = (chunk&7)*8;
    u32x4 p;
    #pragma unroll
    for (int k=0;k<4;k++)
      p[k] = (unsigned)tile[c8+2*k][r] | ((unsigned)tile[c8+2*k+1][r] << 16);
    *(u32x4*)(ob + (size_t)r*CDIM + c8) = p;
  }
}

// ---- k/v GEMM: BK=64 via two split 128x32 half-tiles (r6 proven body) ----
__global__ __launch_bounds__(256) void k_gemm_kv(const unsigned short* __restrict__ A,
                                                 const unsigned short* __restrict__ Bt,
                                                 unsigned short* __restrict__ KV){
  __shared__ unsigned short As[2][128*32];   // 16 KB
  __shared__ unsigned short Bs[2][128*32];   // 16 KB
  int b = blockIdx.z;
  int n0 = blockIdx.x*128, o0 = blockIdx.y*128;
  const unsigned short* Bb = Bt + (size_t)b*NSEQ*CDIM;
  unsigned short* Cb = KV + (size_t)b*1024*NSEQ;
  int t = threadIdx.x, w = t>>6, l = t&63;
  int lr = l&15, kq = (l>>4)*8;
  int wr = (w>>1)*64, wc = (w&1)*64;
  f32x4 acc[4][4];
  #pragma unroll
  for (int mi=0;mi<4;mi++)
    #pragma unroll
    for (int ni=0;ni<4;ni++) acc[mi][ni] = (f32x4){0.f,0.f,0.f,0.f};
  for (int k0=0;k0<CDIM;k0+=64){
    #pragma unroll
    for (int h=0;h<2;++h){
      #pragma unroll
      for (int it=0;it<2;++it){
        int chunk = it*256 + t;
        int row = chunk>>2, kc = (chunk&3)*8;
        gld_lds16(A  + (size_t)(o0+row)*CDIM + k0 + h*32 + kc, (char*)As[h] + (size_t)chunk*16);
        gld_lds16(Bb + (size_t)(n0+row)*CDIM + k0 + h*32 + kc, (char*)Bs[h] + (size_t)chunk*16);
      }
    }
    __syncthreads();
    #pragma unroll
    for (int h=0;h<2;++h){
      short8 af[4], bfv[4];
      #pragma unroll
      for (int mi=0;mi<4;mi++) af[mi]  = *(const short8*)&As[h][(wr + mi*16 + lr)*32 + kq];
      #pragma unroll
      for (int ni=0;ni<4;ni++) bfv[ni] = *(const short8*)&Bs[h][(wc + ni*16 + lr)*32 + kq];
      #pragma unroll
      for (int mi=0;mi<4;mi++)
        #pragma unroll
        for (int ni=0;ni<4;ni++)
          acc[mi][ni] = __builtin_amdgcn_mfma_f32_16x16x32_bf16(af[mi], bfv[ni], acc[mi][ni], 0, 0, 0);
    }
    __syncthreads();
  }
  #pragma unroll
  for (int mi=0;mi<4;mi++)
    #pragma unroll
    for (int ni=0;ni<4;ni++)
      #pragma unroll
      for (int r=0;r<4;r++){
        int row = o0 + wr + mi*16 + (l>>4)*4 + r;
        int col = n0 + wc + ni*16 + lr;
        Cb[(size_t)row*NSEQ + col] = f2bf(acc[mi][ni][r]);
      }
}

// ---- q GEMM (BK=64 split halves) + in-register head-softmax -> qsmT ----
#define TS 136
__global__ __launch_bounds__(256) void k_gemm_q(const unsigned short* __restrict__ A,
                                                const unsigned short* __restrict__ Bt,
                                                unsigned short* __restrict__ qsmT){
  __shared__ unsigned short smem[128*128];   // 32 KB: 4x 128x32 halves; epilogue tile aliases
  int b = blockIdx.z;
  int n0 = blockIdx.x*128, o0 = blockIdx.y*128;
  const unsigned short* Bb = Bt + (size_t)b*NSEQ*CDIM;
  int t = threadIdx.x, w = t>>6, l = t&63;
  int lr = l&15, kq = (l>>4)*8;
  int wr = (w>>1)*64, wc = (w&1)*64;
  f32x4 acc[4][4];
  #pragma unroll
  for (int mi=0;mi<4;mi++)
    #pragma unroll
    for (int ni=0;ni<4;ni++) acc[mi][ni] = (f32x4){0.f,0.f,0.f,0.f};
  for (int k0=0;k0<CDIM;k0+=64){
    #pragma unroll
    for (int h=0;h<2;++h){
      unsigned short* Ash = smem + h*4096;
      unsigned short* Bsh = smem + 8192 + h*4096;
      #pragma unroll
      for (int it=0;it<2;++it){
        int chunk = it*256 + t;
        int row = chunk>>2, kc = (chunk&3)*8;
        gld_lds16(A  + (size_t)(o0+row)*CDIM + k0 + h*32 + kc, (char*)Ash + (size_t)chunk*16);
        gld_lds16(Bb + (size_t)(n0+row)*CDIM + k0 + h*32 + kc, (char*)Bsh + (size_t)chunk*16);
      }
    }
    __syncthreads();
    #pragma unroll
    for (int h=0;h<2;++h){
      const unsigned short* Ash = smem + h*4096;
      const unsigned short* Bsh = smem + 8192 + h*4096;
      short8 af[4], bfv[4];
      #pragma unroll
      for (int mi=0;mi<4;mi++) af[mi]  = *(const short8*)&Ash[(wr + mi*16 + lr)*32 + kq];
      #pragma unroll
      for (int ni=0;ni<4;ni++) bfv[ni] = *(const short8*)&Bsh[(wc + ni*16 + lr)*32 + kq];
      #pragma unroll
      for (int mi=0;mi<4;mi++)
        #pragma unroll
        for (int ni=0;ni<4;ni++)
          acc[mi][ni] = __builtin_amdgcn_mfma_f32_16x16x32_bf16(af[mi], bfv[ni], acc[mi][ni], 0, 0, 0);
    }
    __syncthreads();
  }
  unsigned pk[4][4][2];
  #pragma unroll
  for (int ni=0;ni<4;ni++){
    float mx = -1e30f;
    #pragma unroll
    for (int mi=0;mi<4;mi++)
      #pragma unroll
      for (int r=0;r<4;r++) mx = fmaxf(mx, acc[mi][ni][r]);
    mx = fmaxf(mx, __shfl_xor(mx, 16, 64));
    mx = fmaxf(mx, __shfl_xor(mx, 32, 64));
    float s = 0.f;
    #pragma unroll
    for (int mi=0;mi<4;mi++)
      #pragma unroll
      for (int r=0;r<4;r++){
        float p = __expf(acc[mi][ni][r] - mx);
        acc[mi][ni][r] = p; s += p;
      }
    s += __shfl_xor(s, 16, 64);
    s += __shfl_xor(s, 32, 64);
    float inv = 0.125f / s;
    #pragma unroll
    for (int mi=0;mi<4;mi++){
      pk[mi][ni][0] = pack2(acc[mi][ni][0]*inv, acc[mi][ni][1]*inv);
      pk[mi][ni][1] = pack2(acc[mi][ni][2]*inv, acc[mi][ni][3]*inv);
    }
  }
  #pragma unroll
  for (int ck=0;ck<2;++ck){
    if ((w&1) == ck){
      #pragma unroll
      for (int mi=0;mi<4;mi++)
        #pragma unroll
        for (int ni=0;ni<4;ni++){
          int idx = (ni*16 + lr)*TS + wr + mi*16 + (l>>4)*4;
          u32x2 p; p[0] = pk[mi][ni][0]; p[1] = pk[mi][ni][1];
          *(u32x2*)&smem[idx] = p;
        }
    }
    __syncthreads();
    int col = t>>2, rs = (t&3)*32;
    unsigned short* dst = qsmT + ((size_t)b*NSEQ + n0 + ck*64 + col)*CDIM + o0 + rs;
    #pragma unroll
    for (int j=0;j<4;++j)
      *(u32x4*)(dst + j*8) = *(const u32x4*)&smem[col*TS + rs + j*8];
    __syncthreads();
  }
}

// ---- partial context over n-chunk (512 cols), NO max pass: exp(k) directly ----
__global__ __launch_bounds__(256) void k_context(const unsigned short* __restrict__ KV,
                                                 float* __restrict__ ctx8,
                                                 float* __restrict__ sump){
  __shared__ unsigned short Vs[64*64];
  int m = blockIdx.x, b = blockIdx.y, ch = blockIdx.z;
  int t = threadIdx.x, w = t>>6, l = t&63;
  int lr = l&15, kq = (l>>4)*8;
  const unsigned short* kbase = KV + ((size_t)b*1024 + m*64)*NSEQ;
  const unsigned short* vbase = KV + ((size_t)b*1024 + 512 + m*64)*NSEQ;
  int irow = w*16 + lr;
  int sub = l>>4;
  int nbeg = ch*512;
  float rsum = 0.f;
  f32x4 acc[4];
  #pragma unroll
  for (int jf=0;jf<4;++jf) acc[jf] = (f32x4){0.f,0.f,0.f,0.f};
  for (int n0=nbeg;n0<nbeg+512;n0+=64){
    #pragma unroll
    for (int it=0;it<2;++it){
      int chunk = it*256 + t;
      int row = chunk>>3, kc = (chunk&7)*8;
      gld_lds16(vbase + (size_t)row*NSEQ + n0 + kc, (char*)Vs + (size_t)chunk*16);
    }
    __syncthreads();
    #pragma unroll
    for (int kk=0;kk<2;++kk){
      u32x4 kraw = *(const u32x4*)(kbase + (size_t)irow*NSEQ + n0 + kk*32 + kq);
      short8 af;
      #pragma unroll
      for (int c=0;c<4;++c){
        unsigned u = kraw[c];
        float f0 = __expf(bf2f((unsigned short)u));
        float f1 = __expf(bf2f((unsigned short)(u>>16)));
        rsum += f0 + f1;
        af[c*2]   = (short)f2bf(f0);
        af[c*2+1] = (short)f2bf(f1);
      }
      #pragma unroll
      for (int jf=0;jf<4;++jf){
        short8 bv = *(const short8*)&Vs[(jf*16+lr)*64 + kk*32 + kq];
        acc[jf] = __builtin_amdgcn_mfma_f32_16x16x32_bf16(af, bv, acc[jf], 0, 0, 0);
      }
    }
    __syncthreads();
  }
  rsum += __shfl_xor(rsum, 16, 64);
  rsum += __shfl_xor(rsum, 32, 64);
  size_t sbase = (((size_t)ch*NB + b)*NHEAD + m)*64;
  if (sub == 0) sump[sbase + irow] = rsum;
  float* cb = ctx8 + (((size_t)ch*NB + b)*NHEAD + m)*4096;
  #pragma unroll
  for (int jf=0;jf<4;++jf)
    #pragma unroll
    for (int r=0;r<4;++r){
      int i = w*16 + (l>>4)*4 + r;
      int j = jf*16 + lr;
      cb[i*64 + j] = acc[jf][r];
    }
}

// ---- W_eff: plain-sum merge of 8 chunk-partials, then fold w_out ----
__global__ __launch_bounds__(256) void k_weff(const float* __restrict__ ctx8,
                                              const float* __restrict__ sump,
                                              const float* __restrict__ wout,
                                              unsigned short* __restrict__ weff){
  __shared__ float cs[64][65];
  __shared__ float invZ[64];
  int m = blockIdx.x, b = blockIdx.y, z = blockIdx.z;
  int t = threadIdx.x, w = t>>6, l = t&63;
  const size_t chs = (size_t)NB*NHEAD*4096;
  const size_t sts = (size_t)NB*NHEAD*64;
  size_t sb = ((size_t)b*NHEAD + m)*64;
  if (t < 64){
    float Z = 0.f;
    #pragma unroll
    for (int c=0;c<8;++c) Z += sump[sb + c*sts + t];
    invZ[t] = 1.f/Z;
  }
  __syncthreads();
  const float* cb = ctx8 + ((size_t)b*NHEAD + m)*4096;
  for (int idx=t; idx<4096; idx+=256){
    int i = idx>>6;
    float v = 0.f;
    #pragma unroll
    for (int c=0;c<8;++c) v += cb[idx + c*chs];
    cs[i][idx&63] = v * invZ[i];
  }
  __syncthreads();
  for (int oo=0;oo<32;++oo){
    int o = z*128 + w*32 + oo;
    float acc = 0.f;
    #pragma unroll
    for (int j=0;j<64;++j) acc += wout[(size_t)o*CDIM + m*64 + j] * cs[l][j];
    weff[((size_t)b*CDIM + o)*CDIM + m*64 + l] = f2bf(acc);
  }
}

// ---- fused final GEMM + bias + channel-LN: 512(o) x 128(n), BK=64 split-half.
//      LDS exactly 80 KB (As 2x32K + Bs 2x8K); LN stats alias dead Bs region. ----
__global__ __launch_bounds__(512) void k_out_ln(const unsigned short* __restrict__ Weff,
                                                const unsigned short* __restrict__ QT,
                                                const float* __restrict__ bias,
                                                const float* __restrict__ g,
                                                float* __restrict__ out){
  __shared__ char pool[81920];
  unsigned short* As0 = (unsigned short*)pool;             // 512x32
  unsigned short* As1 = (unsigned short*)(pool + 32768);   // 512x32
  unsigned short* Bs0 = (unsigned short*)(pool + 65536);   // 128x32
  unsigned short* Bs1 = (unsigned short*)(pool + 73728);   // 128x32
  int b = blockIdx.y, n0 = blockIdx.x*128;
  const unsigned short* Ab = Weff + (size_t)b*CDIM*CDIM;
  const unsigned short* Bb = QT + ((size_t)b*NSEQ + n0)*CDIM;
  int t = threadIdx.x, w = t>>6, l = t&63;
  int lr = l&15, kq = (l>>4)*8;
  f32x4 acc[4][8];
  #pragma unroll
  for (int mi=0;mi<4;mi++)
    #pragma unroll
    for (int ni=0;ni<8;ni++) acc[mi][ni] = (f32x4){0.f,0.f,0.f,0.f};
  for (int k0=0;k0<CDIM;k0+=64){
    #pragma unroll
    for (int it=0;it<4;++it){
      int chunk = it*512 + t;
      int row = chunk>>2, kc = (chunk&3)*8;
      gld_lds16(Ab + (size_t)row*CDIM + k0 + kc,      (char*)As0 + (size_t)chunk*16);
      gld_lds16(Ab + (size_t)row*CDIM + k0 + 32 + kc, (char*)As1 + (size_t)chunk*16);
    }
    {
      int row = t>>2, kc = (t&3)*8;
      gld_lds16(Bb + (size_t)row*CDIM + k0 + kc,      (char*)Bs0 + (size_t)t*16);
      gld_lds16(Bb + (size_t)row*CDIM + k0 + 32 + kc, (char*)Bs1 + (size_t)t*16);
    }
    __syncthreads();
    #pragma unroll
    for (int h=0;h<2;++h){
      const unsigned short* Ash = h ? As1 : As0;
      const unsigned short* Bsh = h ? Bs1 : Bs0;
      short8 af[4], bfv[8];
      #pragma unroll
      for (int mi=0;mi<4;mi++) af[mi]  = *(const short8*)&Ash[(w*64 + mi*16 + lr)*32 + kq];
      #pragma unroll
      for (int ni=0;ni<8;ni++) bfv[ni] = *(const short8*)&Bsh[(ni*16 + lr)*32 + kq];
      #pragma unroll
      for (int mi=0;mi<4;mi++)
        #pragma unroll
        for (int ni=0;ni<8;ni++)
          acc[mi][ni] = __builtin_amdgcn_mfma_f32_16x16x32_bf16(af[mi], bfv[ni], acc[mi][ni], 0, 0, 0);
    }
    __syncthreads();
  }
  // ---- bias + LN; stats alias the (dead) Bs region ----
  float* lnS  = (float*)(pool + 65536);
  float* lnS2 = lnS + 128;
  if (t < 128){ lnS[t] = 0.f; lnS2[t] = 0.f; }
  __syncthreads();
  float ps[8], ps2[8];
  #pragma unroll
  for (int ni=0;ni<8;ni++){ ps[ni]=0.f; ps2[ni]=0.f; }
  #pragma unroll
  for (int mi=0;mi<4;mi++)
    #pragma unroll
    for (int r=0;r<4;r++){
      int row = w*64 + mi*16 + (l>>4)*4 + r;
      float bb = bias[row];
      #pragma unroll
      for (int ni=0;ni<8;ni++){
        float v = acc[mi][ni][r] + bb;
        acc[mi][ni][r] = v;
        ps[ni] += v; ps2[ni] += v*v;
      }
    }
  #pragma unroll
  for (int ni=0;ni<8;ni++){
    ps[ni]  += __shfl_xor(ps[ni], 16, 64);  ps[ni]  += __shfl_xor(ps[ni], 32, 64);
    ps2[ni] += __shfl_xor(ps2[ni], 16, 64); ps2[ni] += __shfl_xor(ps2[ni], 32, 64);
  }
  if ((l>>4) == 0){
    #pragma unroll
    for (int ni=0;ni<8;ni++){
      atomicAdd(&lnS[ni*16+lr],  ps[ni]);
      atomicAdd(&lnS2[ni*16+lr], ps2[ni]);
    }
  }
  __syncthreads();
  if (t < 128){
    float mean = lnS[t]*(1.f/512.f);
    float var  = lnS2[t]*(1.f/512.f) - mean*mean;
    lnS[t] = mean; lnS2[t] = rsqrtf(var + 1e-5f);
  }
  __syncthreads();
  float* ob = out + (size_t)b*CDIM*NSEQ + n0;
  #pragma unroll
  for (int ni=0;ni<8;ni++){
    int col = ni*16 + lr;
    float mean = lnS[col], rstd = lnS2[col];
    #pragma unroll
    for (int mi=0;mi<4;mi++)
      #pragma unroll
      for (int r=0;r<4;r++){
        int row = w*64 + mi*16 + (l>>4)*4 + r;
        ob[(size_t)row*NSEQ + col] = (acc[mi][ni][r] - mean)*rstd*g[row];
      }
  }
}

extern "C" void kernel_launch(void* const* d_in, const int* in_sizes, int n_in,
                              void* d_out, int out_size, void* d_ws, size_t ws_size,
                              hipStream_t stream){
  const float* x     = (const float*)d_in[0];
  const float* w_qkv = (const float*)d_in[1];
  const float* w_out = (const float*)d_in[2];
  const float* b_out = (const float*)d_in[3];
  const float* g_out = (const float*)d_in[4];
  float* out = (float*)d_out;
  char* ws = (char*)d_ws;

  size_t off = 0;
  unsigned short* wq_bf = (unsigned short*)(ws + off); off += (size_t)O3*CDIM*2;          // 1.5 MB
  char* xT_region = ws + off;                          off += (size_t)NB*NSEQ*CDIM*2;     // 67 MB
  unsigned short* qkv_kv = (unsigned short*)(ws + off); off += (size_t)NB*1024*NSEQ*2;    // 134 MB
  unsigned short* qsmT   = (unsigned short*)(ws + off); off += (size_t)NB*NSEQ*CDIM*2;    // 67 MB
  if (off > ws_size) return;
  unsigned short* xT = (unsigned short*)xT_region;
  // aliases into xT region (xT dead after both GEMMs):
  float* sump = (float*)(xT_region);                        // 256 KB (8 chunks)
  float* ctx8 = (float*)(xT_region + (1<<20));              // 16.8 MB (8 chunks)
  unsigned short* weff = (unsigned short*)(xT_region + (20<<20)); // 8.4 MB

  k_conv_w     <<<O3*CDIM/1024, 256, 0, stream>>>(w_qkv, wq_bf);
  k_transpose_x<<<dim3(NSEQ/64, CDIM/64, NB), 256, 0, stream>>>(x, xT);
  k_gemm_kv    <<<dim3(NSEQ/128, 8, NB), 256, 0, stream>>>(wq_bf + (size_t)512*CDIM, xT, qkv_kv);
  k_gemm_q     <<<dim3(NSEQ/128, 4, NB), 256, 0, stream>>>(wq_bf, xT, qsmT);
  k_context    <<<dim3(NHEAD, NB, 8), 256, 0, stream>>>(qkv_kv, ctx8, sump);
  k_weff       <<<dim3(NHEAD, NB, 4), 256, 0, stream>>>(ctx8, sump, w_out, weff);
  k_out_ln     <<<dim3(NSEQ/128, NB), 512, 0, stream>>>(weff, qsmT, b_out, g_out, out);
}

// Round 15
// 362.909 us; speedup vs baseline: 1.1035x; 1.0087x over previous
//
#include <hip/hip_runtime.h>

#define NB 16
#define CDIM 512
#define NHEAD 8
#define DHEAD 64
#define NSEQ 4096
#define O3 1536

typedef __attribute__((ext_vector_type(8))) short short8;
typedef __attribute__((ext_vector_type(4))) float f32x4;
typedef __attribute__((ext_vector_type(4))) unsigned u32x4;
typedef __attribute__((ext_vector_type(2))) unsigned u32x2;
typedef __attribute__((ext_vector_type(4))) float fvec4;

__device__ __forceinline__ float bf2f(unsigned short u){
  union { unsigned u; float f; } v; v.u = ((unsigned)u) << 16; return v.f;
}
__device__ __forceinline__ unsigned short f2bf(float f){
  union { float f; unsigned u; } v; v.f = f;
  unsigned r = v.u + 0x7fffu + ((v.u >> 16) & 1u);
  return (unsigned short)(r >> 16);
}
__device__ __forceinline__ unsigned pack2(float a, float b){
  return (unsigned)f2bf(a) | ((unsigned)f2bf(b) << 16);
}
__device__ __forceinline__ void gld_lds16(const void* g, void* l){
  __builtin_amdgcn_global_load_lds(
      (const __attribute__((address_space(1))) unsigned*)g,
      (__attribute__((address_space(3))) unsigned*)l, 16, 0, 0);
}

// ---- w_qkv f32 -> bf16 ----
__global__ __launch_bounds__(256) void k_conv_w(const float* __restrict__ w,
                                                unsigned short* __restrict__ o){
  int i = (blockIdx.x*256 + threadIdx.x)*4;
  fvec4 v = *(const fvec4*)(w + i);
  u32x2 p; p[0] = pack2(v[0], v[1]); p[1] = pack2(v[2], v[3]);
  *(u32x2*)(o + i) = p;
}

// ---- x [b][c][n] f32 -> xT [b][n][c] bf16; 16B reads, 16B writes ----
__global__ __launch_bounds__(256) void k_transpose_x(const float* __restrict__ x,
                                                     unsigned short* __restrict__ xT){
  __shared__ unsigned short tile[64][65];
  int b = blockIdx.z, c0 = blockIdx.y*64, n0 = blockIdx.x*64;
  int t = threadIdx.x;
  const float* xb = x + ((size_t)b*CDIM + c0)*NSEQ + n0;
  #pragma unroll
  for (int i=0;i<4;i++){
    int idx = t + i*256;
    int r = idx>>4, c4 = (idx&15)*4;
    fvec4 v = *(const fvec4*)(xb + (size_t)r*NSEQ + c4);
    tile[r][c4]   = f2bf(v[0]);
    tile[r][c4+1] = f2bf(v[1]);
    tile[r][c4+2] = f2bf(v[2]);
    tile[r][c4+3] = f2bf(v[3]);
  }
  __syncthreads();
  unsigned short* ob = xT + ((size_t)b*NSEQ + n0)*CDIM + c0;
  #pragma unroll
  for (int i=0;i<2;i++){
    int chunk = t + i*256;
    int r = chunk>>3, c8 = (chunk&7)*8;
    u32x4 p;
    #pragma unroll
    for (int k=0;k<4;k++)
      p[k] = (unsigned)tile[c8+2*k][r] | ((unsigned)tile[c8+2*k+1][r] << 16);
    *(u32x4*)(ob + (size_t)r*CDIM + c8) = p;
  }
}

// ---- k/v GEMM: BK=64 via two split 128x32 half-tiles (r6 proven body) ----
__global__ __launch_bounds__(256) void k_gemm_kv(const unsigned short* __restrict__ A,
                                                 const unsigned short* __restrict__ Bt,
                                                 unsigned short* __restrict__ KV){
  __shared__ unsigned short As[2][128*32];   // 16 KB
  __shared__ unsigned short Bs[2][128*32];   // 16 KB
  int b = blockIdx.z;
  int n0 = blockIdx.x*128, o0 = blockIdx.y*128;
  const unsigned short* Bb = Bt + (size_t)b*NSEQ*CDIM;
  unsigned short* Cb = KV + (size_t)b*1024*NSEQ;
  int t = threadIdx.x, w = t>>6, l = t&63;
  int lr = l&15, kq = (l>>4)*8;
  int wr = (w>>1)*64, wc = (w&1)*64;
  f32x4 acc[4][4];
  #pragma unroll
  for (int mi=0;mi<4;mi++)
    #pragma unroll
    for (int ni=0;ni<4;ni++) acc[mi][ni] = (f32x4){0.f,0.f,0.f,0.f};
  for (int k0=0;k0<CDIM;k0+=64){
    #pragma unroll
    for (int h=0;h<2;++h){
      #pragma unroll
      for (int it=0;it<2;++it){
        int chunk = it*256 + t;
        int row = chunk>>2, kc = (chunk&3)*8;
        gld_lds16(A  + (size_t)(o0+row)*CDIM + k0 + h*32 + kc, (char*)As[h] + (size_t)chunk*16);
        gld_lds16(Bb + (size_t)(n0+row)*CDIM + k0 + h*32 + kc, (char*)Bs[h] + (size_t)chunk*16);
      }
    }
    __syncthreads();
    #pragma unroll
    for (int h=0;h<2;++h){
      short8 af[4], bfv[4];
      #pragma unroll
      for (int mi=0;mi<4;mi++) af[mi]  = *(const short8*)&As[h][(wr + mi*16 + lr)*32 + kq];
      #pragma unroll
      for (int ni=0;ni<4;ni++) bfv[ni] = *(const short8*)&Bs[h][(wc + ni*16 + lr)*32 + kq];
      #pragma unroll
      for (int mi=0;mi<4;mi++)
        #pragma unroll
        for (int ni=0;ni<4;ni++)
          acc[mi][ni] = __builtin_amdgcn_mfma_f32_16x16x32_bf16(af[mi], bfv[ni], acc[mi][ni], 0, 0, 0);
    }
    __syncthreads();
  }
  #pragma unroll
  for (int mi=0;mi<4;mi++)
    #pragma unroll
    for (int ni=0;ni<4;ni++)
      #pragma unroll
      for (int r=0;r<4;r++){
        int row = o0 + wr + mi*16 + (l>>4)*4 + r;
        int col = n0 + wc + ni*16 + lr;
        Cb[(size_t)row*NSEQ + col] = f2bf(acc[mi][ni][r]);
      }
}

// ---- q GEMM (BK=64 split halves) + in-register head-softmax -> qsmT ----
#define TS 136
__global__ __launch_bounds__(256) void k_gemm_q(const unsigned short* __restrict__ A,
                                                const unsigned short* __restrict__ Bt,
                                                unsigned short* __restrict__ qsmT){
  __shared__ unsigned short smem[128*128];   // 32 KB: 4x 128x32 halves; epilogue tile aliases
  int b = blockIdx.z;
  int n0 = blockIdx.x*128, o0 = blockIdx.y*128;
  const unsigned short* Bb = Bt + (size_t)b*NSEQ*CDIM;
  int t = threadIdx.x, w = t>>6, l = t&63;
  int lr = l&15, kq = (l>>4)*8;
  int wr = (w>>1)*64, wc = (w&1)*64;
  f32x4 acc[4][4];
  #pragma unroll
  for (int mi=0;mi<4;mi++)
    #pragma unroll
    for (int ni=0;ni<4;ni++) acc[mi][ni] = (f32x4){0.f,0.f,0.f,0.f};
  for (int k0=0;k0<CDIM;k0+=64){
    #pragma unroll
    for (int h=0;h<2;++h){
      unsigned short* Ash = smem + h*4096;
      unsigned short* Bsh = smem + 8192 + h*4096;
      #pragma unroll
      for (int it=0;it<2;++it){
        int chunk = it*256 + t;
        int row = chunk>>2, kc = (chunk&3)*8;
        gld_lds16(A  + (size_t)(o0+row)*CDIM + k0 + h*32 + kc, (char*)Ash + (size_t)chunk*16);
        gld_lds16(Bb + (size_t)(n0+row)*CDIM + k0 + h*32 + kc, (char*)Bsh + (size_t)chunk*16);
      }
    }
    __syncthreads();
    #pragma unroll
    for (int h=0;h<2;++h){
      const unsigned short* Ash = smem + h*4096;
      const unsigned short* Bsh = smem + 8192 + h*4096;
      short8 af[4], bfv[4];
      #pragma unroll
      for (int mi=0;mi<4;mi++) af[mi]  = *(const short8*)&Ash[(wr + mi*16 + lr)*32 + kq];
      #pragma unroll
      for (int ni=0;ni<4;ni++) bfv[ni] = *(const short8*)&Bsh[(wc + ni*16 + lr)*32 + kq];
      #pragma unroll
      for (int mi=0;mi<4;mi++)
        #pragma unroll
        for (int ni=0;ni<4;ni++)
          acc[mi][ni] = __builtin_amdgcn_mfma_f32_16x16x32_bf16(af[mi], bfv[ni], acc[mi][ni], 0, 0, 0);
    }
    __syncthreads();
  }
  unsigned pk[4][4][2];
  #pragma unroll
  for (int ni=0;ni<4;ni++){
    float mx = -1e30f;
    #pragma unroll
    for (int mi=0;mi<4;mi++)
      #pragma unroll
      for (int r=0;r<4;r++) mx = fmaxf(mx, acc[mi][ni][r]);
    mx = fmaxf(mx, __shfl_xor(mx, 16, 64));
    mx = fmaxf(mx, __shfl_xor(mx, 32, 64));
    float s = 0.f;
    #pragma unroll
    for (int mi=0;mi<4;mi++)
      #pragma unroll
      for (int r=0;r<4;r++){
        float p = __expf(acc[mi][ni][r] - mx);
        acc[mi][ni][r] = p; s += p;
      }
    s += __shfl_xor(s, 16, 64);
    s += __shfl_xor(s, 32, 64);
    float inv = 0.125f / s;
    #pragma unroll
    for (int mi=0;mi<4;mi++){
      pk[mi][ni][0] = pack2(acc[mi][ni][0]*inv, acc[mi][ni][1]*inv);
      pk[mi][ni][1] = pack2(acc[mi][ni][2]*inv, acc[mi][ni][3]*inv);
    }
  }
  #pragma unroll
  for (int ck=0;ck<2;++ck){
    if ((w&1) == ck){
      #pragma unroll
      for (int mi=0;mi<4;mi++)
        #pragma unroll
        for (int ni=0;ni<4;ni++){
          int idx = (ni*16 + lr)*TS + wr + mi*16 + (l>>4)*4;
          u32x2 p; p[0] = pk[mi][ni][0]; p[1] = pk[mi][ni][1];
          *(u32x2*)&smem[idx] = p;
        }
    }
    __syncthreads();
    int col = t>>2, rs = (t&3)*32;
    unsigned short* dst = qsmT + ((size_t)b*NSEQ + n0 + ck*64 + col)*CDIM + o0 + rs;
    #pragma unroll
    for (int j=0;j<4;++j)
      *(u32x4*)(dst + j*8) = *(const u32x4*)&smem[col*TS + rs + j*8];
    __syncthreads();
  }
}

// ---- partial context over n-chunk (512 cols), NO max pass: exp(k) directly ----
__global__ __launch_bounds__(256) void k_context(const unsigned short* __restrict__ KV,
                                                 float* __restrict__ ctx8,
                                                 float* __restrict__ sump){
  __shared__ unsigned short Vs[64*64];
  int m = blockIdx.x, b = blockIdx.y, ch = blockIdx.z;
  int t = threadIdx.x, w = t>>6, l = t&63;
  int lr = l&15, kq = (l>>4)*8;
  const unsigned short* kbase = KV + ((size_t)b*1024 + m*64)*NSEQ;
  const unsigned short* vbase = KV + ((size_t)b*1024 + 512 + m*64)*NSEQ;
  int irow = w*16 + lr;
  int sub = l>>4;
  int nbeg = ch*512;
  float rsum = 0.f;
  f32x4 acc[4];
  #pragma unroll
  for (int jf=0;jf<4;++jf) acc[jf] = (f32x4){0.f,0.f,0.f,0.f};
  for (int n0=nbeg;n0<nbeg+512;n0+=64){
    #pragma unroll
    for (int it=0;it<2;++it){
      int chunk = it*256 + t;
      int row = chunk>>3, kc = (chunk&7)*8;
      gld_lds16(vbase + (size_t)row*NSEQ + n0 + kc, (char*)Vs + (size_t)chunk*16);
    }
    __syncthreads();
    #pragma unroll
    for (int kk=0;kk<2;++kk){
      u32x4 kraw = *(const u32x4*)(kbase + (size_t)irow*NSEQ + n0 + kk*32 + kq);
      short8 af;
      #pragma unroll
      for (int c=0;c<4;++c){
        unsigned u = kraw[c];
        float f0 = __expf(bf2f((unsigned short)u));
        float f1 = __expf(bf2f((unsigned short)(u>>16)));
        rsum += f0 + f1;
        af[c*2]   = (short)f2bf(f0);
        af[c*2+1] = (short)f2bf(f1);
      }
      #pragma unroll
      for (int jf=0;jf<4;++jf){
        short8 bv = *(const short8*)&Vs[(jf*16+lr)*64 + kk*32 + kq];
        acc[jf] = __builtin_amdgcn_mfma_f32_16x16x32_bf16(af, bv, acc[jf], 0, 0, 0);
      }
    }
    __syncthreads();
  }
  rsum += __shfl_xor(rsum, 16, 64);
  rsum += __shfl_xor(rsum, 32, 64);
  size_t sbase = (((size_t)ch*NB + b)*NHEAD + m)*64;
  if (sub == 0) sump[sbase + irow] = rsum;
  float* cb = ctx8 + (((size_t)ch*NB + b)*NHEAD + m)*4096;
  #pragma unroll
  for (int jf=0;jf<4;++jf)
    #pragma unroll
    for (int r=0;r<4;++r){
      int i = w*16 + (l>>4)*4 + r;
      int j = jf*16 + lr;
      cb[i*64 + j] = acc[jf][r];
    }
}

// ---- W_eff: plain-sum merge of 8 chunk-partials, then fold w_out ----
__global__ __launch_bounds__(256) void k_weff(const float* __restrict__ ctx8,
                                              const float* __restrict__ sump,
                                              const float* __restrict__ wout,
                                              unsigned short* __restrict__ weff){
  __shared__ float cs[64][65];
  __shared__ float invZ[64];
  int m = blockIdx.x, b = blockIdx.y, z = blockIdx.z;
  int t = threadIdx.x, w = t>>6, l = t&63;
  const size_t chs = (size_t)NB*NHEAD*4096;
  const size_t sts = (size_t)NB*NHEAD*64;
  size_t sb = ((size_t)b*NHEAD + m)*64;
  if (t < 64){
    float Z = 0.f;
    #pragma unroll
    for (int c=0;c<8;++c) Z += sump[sb + c*sts + t];
    invZ[t] = 1.f/Z;
  }
  __syncthreads();
  const float* cb = ctx8 + ((size_t)b*NHEAD + m)*4096;
  for (int idx=t; idx<4096; idx+=256){
    int i = idx>>6;
    float v = 0.f;
    #pragma unroll
    for (int c=0;c<8;++c) v += cb[idx + c*chs];
    cs[i][idx&63] = v * invZ[i];
  }
  __syncthreads();
  for (int oo=0;oo<32;++oo){
    int o = z*128 + w*32 + oo;
    float acc = 0.f;
    #pragma unroll
    for (int j=0;j<64;++j) acc += wout[(size_t)o*CDIM + m*64 + j] * cs[l][j];
    weff[((size_t)b*CDIM + o)*CDIM + m*64 + l] = f2bf(acc);
  }
}

// ---- fused final GEMM + bias + channel-LN: 512(o) x 128(n), BK=64 split-half.
//      XCD b-locality swizzle: each XCD owns 2 batches -> weff L2-resident. ----
__global__ __launch_bounds__(512) void k_out_ln(const unsigned short* __restrict__ Weff,
                                                const unsigned short* __restrict__ QT,
                                                const float* __restrict__ bias,
                                                const float* __restrict__ g,
                                                float* __restrict__ out){
  __shared__ char pool[81920];
  unsigned short* As0 = (unsigned short*)pool;             // 512x32
  unsigned short* As1 = (unsigned short*)(pool + 32768);   // 512x32
  unsigned short* Bs0 = (unsigned short*)(pool + 65536);   // 128x32
  unsigned short* Bs1 = (unsigned short*)(pool + 73728);   // 128x32
  // bijective swizzle over 512 blocks: xcd = fid&7 owns batches {2*xcd, 2*xcd+1}
  int fid = blockIdx.x + 32*blockIdx.y;
  int xcd = fid & 7, j = fid >> 3;
  int b  = xcd*2 + (j & 1);
  int n0 = (j >> 1) * 128;
  const unsigned short* Ab = Weff + (size_t)b*CDIM*CDIM;
  const unsigned short* Bb = QT + ((size_t)b*NSEQ + n0)*CDIM;
  int t = threadIdx.x, w = t>>6, l = t&63;
  int lr = l&15, kq = (l>>4)*8;
  f32x4 acc[4][8];
  #pragma unroll
  for (int mi=0;mi<4;mi++)
    #pragma unroll
    for (int ni=0;ni<8;ni++) acc[mi][ni] = (f32x4){0.f,0.f,0.f,0.f};
  for (int k0=0;k0<CDIM;k0+=64){
    #pragma unroll
    for (int it=0;it<4;++it){
      int chunk = it*512 + t;
      int row = chunk>>2, kc = (chunk&3)*8;
      gld_lds16(Ab + (size_t)row*CDIM + k0 + kc,      (char*)As0 + (size_t)chunk*16);
      gld_lds16(Ab + (size_t)row*CDIM + k0 + 32 + kc, (char*)As1 + (size_t)chunk*16);
    }
    {
      int row = t>>2, kc = (t&3)*8;
      gld_lds16(Bb + (size_t)row*CDIM + k0 + kc,      (char*)Bs0 + (size_t)t*16);
      gld_lds16(Bb + (size_t)row*CDIM + k0 + 32 + kc, (char*)Bs1 + (size_t)t*16);
    }
    __syncthreads();
    #pragma unroll
    for (int h=0;h<2;++h){
      const unsigned short* Ash = h ? As1 : As0;
      const unsigned short* Bsh = h ? Bs1 : Bs0;
      short8 af[4], bfv[8];
      #pragma unroll
      for (int mi=0;mi<4;mi++) af[mi]  = *(const short8*)&Ash[(w*64 + mi*16 + lr)*32 + kq];
      #pragma unroll
      for (int ni=0;ni<8;ni++) bfv[ni] = *(const short8*)&Bsh[(ni*16 + lr)*32 + kq];
      #pragma unroll
      for (int mi=0;mi<4;mi++)
        #pragma unroll
        for (int ni=0;ni<8;ni++)
          acc[mi][ni] = __builtin_amdgcn_mfma_f32_16x16x32_bf16(af[mi], bfv[ni], acc[mi][ni], 0, 0, 0);
    }
    __syncthreads();
  }
  float* lnS  = (float*)(pool + 65536);
  float* lnS2 = lnS + 128;
  if (t < 128){ lnS[t] = 0.f; lnS2[t] = 0.f; }
  __syncthreads();
  float ps[8], ps2[8];
  #pragma unroll
  for (int ni=0;ni<8;ni++){ ps[ni]=0.f; ps2[ni]=0.f; }
  #pragma unroll
  for (int mi=0;mi<4;mi++)
    #pragma unroll
    for (int r=0;r<4;r++){
      int row = w*64 + mi*16 + (l>>4)*4 + r;
      float bb = bias[row];
      #pragma unroll
      for (int ni=0;ni<8;ni++){
        float v = acc[mi][ni][r] + bb;
        acc[mi][ni][r] = v;
        ps[ni] += v; ps2[ni] += v*v;
      }
    }
  #pragma unroll
  for (int ni=0;ni<8;ni++){
    ps[ni]  += __shfl_xor(ps[ni], 16, 64);  ps[ni]  += __shfl_xor(ps[ni], 32, 64);
    ps2[ni] += __shfl_xor(ps2[ni], 16, 64); ps2[ni] += __shfl_xor(ps2[ni], 32, 64);
  }
  if ((l>>4) == 0){
    #pragma unroll
    for (int ni=0;ni<8;ni++){
      atomicAdd(&lnS[ni*16+lr],  ps[ni]);
      atomicAdd(&lnS2[ni*16+lr], ps2[ni]);
    }
  }
  __syncthreads();
  if (t < 128){
    float mean = lnS[t]*(1.f/512.f);
    float var  = lnS2[t]*(1.f/512.f) - mean*mean;
    lnS[t] = mean; lnS2[t] = rsqrtf(var + 1e-5f);
  }
  __syncthreads();
  float* ob = out + (size_t)b*CDIM*NSEQ + n0;
  #pragma unroll
  for (int ni=0;ni<8;ni++){
    int col = ni*16 + lr;
    float mean = lnS[col], rstd = lnS2[col];
    #pragma unroll
    for (int mi=0;mi<4;mi++)
      #pragma unroll
      for (int r=0;r<4;r++){
        int row = w*64 + mi*16 + (l>>4)*4 + r;
        ob[(size_t)row*NSEQ + col] = (acc[mi][ni][r] - mean)*rstd*g[row];
      }
  }
}

extern "C" void kernel_launch(void* const* d_in, const int* in_sizes, int n_in,
                              void* d_out, int out_size, void* d_ws, size_t ws_size,
                              hipStream_t stream){
  const float* x     = (const float*)d_in[0];
  const float* w_qkv = (const float*)d_in[1];
  const float* w_out = (const float*)d_in[2];
  const float* b_out = (const float*)d_in[3];
  const float* g_out = (const float*)d_in[4];
  float* out = (float*)d_out;
  char* ws = (char*)d_ws;

  size_t off = 0;
  unsigned short* wq_bf = (unsigned short*)(ws + off); off += (size_t)O3*CDIM*2;          // 1.5 MB
  char* xT_region = ws + off;                          off += (size_t)NB*NSEQ*CDIM*2;     // 67 MB
  unsigned short* qkv_kv = (unsigned short*)(ws + off); off += (size_t)NB*1024*NSEQ*2;    // 134 MB
  unsigned short* qsmT   = (unsigned short*)(ws + off); off += (size_t)NB*NSEQ*CDIM*2;    // 67 MB
  if (off > ws_size) return;
  unsigned short* xT = (unsigned short*)xT_region;
  // aliases into xT region (xT dead after both GEMMs):
  float* sump = (float*)(xT_region);                        // 256 KB (8 chunks)
  float* ctx8 = (float*)(xT_region + (1<<20));              // 16.8 MB (8 chunks)
  unsigned short* weff = (unsigned short*)(xT_region + (20<<20)); // 8.4 MB

  k_conv_w     <<<O3*CDIM/1024, 256, 0, stream>>>(w_qkv, wq_bf);
  k_transpose_x<<<dim3(NSEQ/64, CDIM/64, NB), 256, 0, stream>>>(x, xT);
  k_gemm_kv    <<<dim3(NSEQ/128, 8, NB), 256, 0, stream>>>(wq_bf + (size_t)512*CDIM, xT, qkv_kv);
  k_gemm_q     <<<dim3(NSEQ/128, 4, NB), 256, 0, stream>>>(wq_bf, xT, qsmT);
  k_context    <<<dim3(NHEAD, NB, 8), 256, 0, stream>>>(qkv_kv, ctx8, sump);
  k_weff       <<<dim3(NHEAD, NB, 4), 256, 0, stream>>>(ctx8, sump, w_out, weff);
  k_out_ln     <<<dim3(NSEQ/128, NB), 512, 0, stream>>>(weff, qsmT, b_out, g_out, out);
}

// Round 16
// 362.512 us; speedup vs baseline: 1.1047x; 1.0011x over previous
//
#include <hip/hip_runtime.h>

#define NB 16
#define CDIM 512
#define NHEAD 8
#define DHEAD 64
#define NSEQ 4096
#define O3 1536

typedef __attribute__((ext_vector_type(8))) short short8;
typedef __attribute__((ext_vector_type(4))) float f32x4;
typedef __attribute__((ext_vector_type(4))) unsigned u32x4;
typedef __attribute__((ext_vector_type(2))) unsigned u32x2;
typedef __attribute__((ext_vector_type(4))) float fvec4;

__device__ __forceinline__ float bf2f(unsigned short u){
  union { unsigned u; float f; } v; v.u = ((unsigned)u) << 16; return v.f;
}
__device__ __forceinline__ unsigned short f2bf(float f){
  union { float f; unsigned u; } v; v.f = f;
  unsigned r = v.u + 0x7fffu + ((v.u >> 16) & 1u);
  return (unsigned short)(r >> 16);
}
__device__ __forceinline__ unsigned pack2(float a, float b){
  return (unsigned)f2bf(a) | ((unsigned)f2bf(b) << 16);
}
__device__ __forceinline__ void gld_lds16(const void* g, void* l){
  __builtin_amdgcn_global_load_lds(
      (const __attribute__((address_space(1))) unsigned*)g,
      (__attribute__((address_space(3))) unsigned*)l, 16, 0, 0);
}

// ---- merged: x transpose (fid<8192) + w_qkv f32->bf16 (fid>=8192) ----
__global__ __launch_bounds__(256) void k_transpose_conv(const float* __restrict__ x,
                                                        const float* __restrict__ wq,
                                                        unsigned short* __restrict__ xT,
                                                        unsigned short* __restrict__ wq_bf){
  __shared__ unsigned short tile[64][65];
  int fid = blockIdx.x;
  int t = threadIdx.x;
  if (fid >= 8192){
    int i = ((fid - 8192)*256 + t)*4;
    fvec4 v = *(const fvec4*)(wq + i);
    u32x2 p; p[0] = pack2(v[0], v[1]); p[1] = pack2(v[2], v[3]);
    *(u32x2*)(wq_bf + i) = p;
    return;
  }
  int b = fid >> 9, c0 = ((fid >> 6) & 7)*64, n0 = (fid & 63)*64;
  const float* xb = x + ((size_t)b*CDIM + c0)*NSEQ + n0;
  #pragma unroll
  for (int i=0;i<4;i++){
    int idx = t + i*256;
    int r = idx>>4, c4 = (idx&15)*4;
    fvec4 v = *(const fvec4*)(xb + (size_t)r*NSEQ + c4);
    tile[r][c4]   = f2bf(v[0]);
    tile[r][c4+1] = f2bf(v[1]);
    tile[r][c4+2] = f2bf(v[2]);
    tile[r][c4+3] = f2bf(v[3]);
  }
  __syncthreads();
  unsigned short* ob = xT + ((size_t)b*NSEQ + n0)*CDIM + c0;
  #pragma unroll
  for (int i=0;i<2;i++){
    int chunk = t + i*256;
    int r = chunk>>3, c8 = (chunk&7)*8;
    u32x4 p;
    #pragma unroll
    for (int k=0;k<4;k++)
      p[k] = (unsigned)tile[c8+2*k][r] | ((unsigned)tile[c8+2*k+1][r] << 16);
    *(u32x4*)(ob + (size_t)r*CDIM + c8) = p;
  }
}

// ---- k/v GEMM: BK=64 split-half body + XCD panel-locality swizzle.
//      xcd=fid&7 owns 2 batches; o0 innermost so B-panel consumers co-reside. ----
__global__ __launch_bounds__(256) void k_gemm_kv(const unsigned short* __restrict__ A,
                                                 const unsigned short* __restrict__ Bt,
                                                 unsigned short* __restrict__ KV){
  __shared__ unsigned short As[2][128*32];   // 16 KB
  __shared__ unsigned short Bs[2][128*32];   // 16 KB
  int fid = blockIdx.x;
  int xcd = fid & 7, j = fid >> 3;
  int b = xcd*2 + (j & 1);
  int j2 = j >> 1;                 // 0..255
  int o0 = (j2 & 7)*128;           // inner: 8 o-tiles share the B-panel
  int n0 = (j2 >> 3)*128;          // 32 n-tiles
  const unsigned short* Bb = Bt + (size_t)b*NSEQ*CDIM;
  unsigned short* Cb = KV + (size_t)b*1024*NSEQ;
  int t = threadIdx.x, w = t>>6, l = t&63;
  int lr = l&15, kq = (l>>4)*8;
  int wr = (w>>1)*64, wc = (w&1)*64;
  f32x4 acc[4][4];
  #pragma unroll
  for (int mi=0;mi<4;mi++)
    #pragma unroll
    for (int ni=0;ni<4;ni++) acc[mi][ni] = (f32x4){0.f,0.f,0.f,0.f};
  for (int k0=0;k0<CDIM;k0+=64){
    #pragma unroll
    for (int h=0;h<2;++h){
      #pragma unroll
      for (int it=0;it<2;++it){
        int chunk = it*256 + t;
        int row = chunk>>2, kc = (chunk&3)*8;
        gld_lds16(A  + (size_t)(o0+row)*CDIM + k0 + h*32 + kc, (char*)As[h] + (size_t)chunk*16);
        gld_lds16(Bb + (size_t)(n0+row)*CDIM + k0 + h*32 + kc, (char*)Bs[h] + (size_t)chunk*16);
      }
    }
    __syncthreads();
    #pragma unroll
    for (int h=0;h<2;++h){
      short8 af[4], bfv[4];
      #pragma unroll
      for (int mi=0;mi<4;mi++) af[mi]  = *(const short8*)&As[h][(wr + mi*16 + lr)*32 + kq];
      #pragma unroll
      for (int ni=0;ni<4;ni++) bfv[ni] = *(const short8*)&Bs[h][(wc + ni*16 + lr)*32 + kq];
      #pragma unroll
      for (int mi=0;mi<4;mi++)
        #pragma unroll
        for (int ni=0;ni<4;ni++)
          acc[mi][ni] = __builtin_amdgcn_mfma_f32_16x16x32_bf16(af[mi], bfv[ni], acc[mi][ni], 0, 0, 0);
    }
    __syncthreads();
  }
  #pragma unroll
  for (int mi=0;mi<4;mi++)
    #pragma unroll
    for (int ni=0;ni<4;ni++)
      #pragma unroll
      for (int r=0;r<4;r++){
        int row = o0 + wr + mi*16 + (l>>4)*4 + r;
        int col = n0 + wc + ni*16 + lr;
        Cb[(size_t)row*NSEQ + col] = f2bf(acc[mi][ni][r]);
      }
}

// ---- q GEMM (BK=64 split halves, XCD swizzle) + in-reg softmax -> qsmT ----
#define TS 136
__global__ __launch_bounds__(256) void k_gemm_q(const unsigned short* __restrict__ A,
                                                const unsigned short* __restrict__ Bt,
                                                unsigned short* __restrict__ qsmT){
  __shared__ unsigned short smem[128*128];   // 32 KB
  int fid = blockIdx.x;
  int xcd = fid & 7, j = fid >> 3;
  int b = xcd*2 + (j & 1);
  int j2 = j >> 1;                 // 0..127
  int o0 = (j2 & 3)*128;           // inner: 4 o-tiles share the B-panel
  int n0 = (j2 >> 2)*128;          // 32 n-tiles
  const unsigned short* Bb = Bt + (size_t)b*NSEQ*CDIM;
  int t = threadIdx.x, w = t>>6, l = t&63;
  int lr = l&15, kq = (l>>4)*8;
  int wr = (w>>1)*64, wc = (w&1)*64;
  f32x4 acc[4][4];
  #pragma unroll
  for (int mi=0;mi<4;mi++)
    #pragma unroll
    for (int ni=0;ni<4;ni++) acc[mi][ni] = (f32x4){0.f,0.f,0.f,0.f};
  for (int k0=0;k0<CDIM;k0+=64){
    #pragma unroll
    for (int h=0;h<2;++h){
      unsigned short* Ash = smem + h*4096;
      unsigned short* Bsh = smem + 8192 + h*4096;
      #pragma unroll
      for (int it=0;it<2;++it){
        int chunk = it*256 + t;
        int row = chunk>>2, kc = (chunk&3)*8;
        gld_lds16(A  + (size_t)(o0+row)*CDIM + k0 + h*32 + kc, (char*)Ash + (size_t)chunk*16);
        gld_lds16(Bb + (size_t)(n0+row)*CDIM + k0 + h*32 + kc, (char*)Bsh + (size_t)chunk*16);
      }
    }
    __syncthreads();
    #pragma unroll
    for (int h=0;h<2;++h){
      const unsigned short* Ash = smem + h*4096;
      const unsigned short* Bsh = smem + 8192 + h*4096;
      short8 af[4], bfv[4];
      #pragma unroll
      for (int mi=0;mi<4;mi++) af[mi]  = *(const short8*)&Ash[(wr + mi*16 + lr)*32 + kq];
      #pragma unroll
      for (int ni=0;ni<4;ni++) bfv[ni] = *(const short8*)&Bsh[(wc + ni*16 + lr)*32 + kq];
      #pragma unroll
      for (int mi=0;mi<4;mi++)
        #pragma unroll
        for (int ni=0;ni<4;ni++)
          acc[mi][ni] = __builtin_amdgcn_mfma_f32_16x16x32_bf16(af[mi], bfv[ni], acc[mi][ni], 0, 0, 0);
    }
    __syncthreads();
  }
  unsigned pk[4][4][2];
  #pragma unroll
  for (int ni=0;ni<4;ni++){
    float mx = -1e30f;
    #pragma unroll
    for (int mi=0;mi<4;mi++)
      #pragma unroll
      for (int r=0;r<4;r++) mx = fmaxf(mx, acc[mi][ni][r]);
    mx = fmaxf(mx, __shfl_xor(mx, 16, 64));
    mx = fmaxf(mx, __shfl_xor(mx, 32, 64));
    float s = 0.f;
    #pragma unroll
    for (int mi=0;mi<4;mi++)
      #pragma unroll
      for (int r=0;r<4;r++){
        float p = __expf(acc[mi][ni][r] - mx);
        acc[mi][ni][r] = p; s += p;
      }
    s += __shfl_xor(s, 16, 64);
    s += __shfl_xor(s, 32, 64);
    float inv = 0.125f / s;
    #pragma unroll
    for (int mi=0;mi<4;mi++){
      pk[mi][ni][0] = pack2(acc[mi][ni][0]*inv, acc[mi][ni][1]*inv);
      pk[mi][ni][1] = pack2(acc[mi][ni][2]*inv, acc[mi][ni][3]*inv);
    }
  }
  #pragma unroll
  for (int ck=0;ck<2;++ck){
    if ((w&1) == ck){
      #pragma unroll
      for (int mi=0;mi<4;mi++)
        #pragma unroll
        for (int ni=0;ni<4;ni++){
          int idx = (ni*16 + lr)*TS + wr + mi*16 + (l>>4)*4;
          u32x2 p; p[0] = pk[mi][ni][0]; p[1] = pk[mi][ni][1];
          *(u32x2*)&smem[idx] = p;
        }
    }
    __syncthreads();
    int col = t>>2, rs = (t&3)*32;
    unsigned short* dst = qsmT + ((size_t)b*NSEQ + n0 + ck*64 + col)*CDIM + o0 + rs;
    #pragma unroll
    for (int j3=0;j3<4;++j3)
      *(u32x4*)(dst + j3*8) = *(const u32x4*)&smem[col*TS + rs + j3*8];
    __syncthreads();
  }
}

// ---- partial context over n-chunk (512 cols), NO max pass: exp(k) directly ----
__global__ __launch_bounds__(256) void k_context(const unsigned short* __restrict__ KV,
                                                 float* __restrict__ ctx8,
                                                 float* __restrict__ sump){
  __shared__ unsigned short Vs[64*64];
  int m = blockIdx.x, b = blockIdx.y, ch = blockIdx.z;
  int t = threadIdx.x, w = t>>6, l = t&63;
  int lr = l&15, kq = (l>>4)*8;
  const unsigned short* kbase = KV + ((size_t)b*1024 + m*64)*NSEQ;
  const unsigned short* vbase = KV + ((size_t)b*1024 + 512 + m*64)*NSEQ;
  int irow = w*16 + lr;
  int sub = l>>4;
  int nbeg = ch*512;
  float rsum = 0.f;
  f32x4 acc[4];
  #pragma unroll
  for (int jf=0;jf<4;++jf) acc[jf] = (f32x4){0.f,0.f,0.f,0.f};
  for (int n0=nbeg;n0<nbeg+512;n0+=64){
    #pragma unroll
    for (int it=0;it<2;++it){
      int chunk = it*256 + t;
      int row = chunk>>3, kc = (chunk&7)*8;
      gld_lds16(vbase + (size_t)row*NSEQ + n0 + kc, (char*)Vs + (size_t)chunk*16);
    }
    __syncthreads();
    #pragma unroll
    for (int kk=0;kk<2;++kk){
      u32x4 kraw = *(const u32x4*)(kbase + (size_t)irow*NSEQ + n0 + kk*32 + kq);
      short8 af;
      #pragma unroll
      for (int c=0;c<4;++c){
        unsigned u = kraw[c];
        float f0 = __expf(bf2f((unsigned short)u));
        float f1 = __expf(bf2f((unsigned short)(u>>16)));
        rsum += f0 + f1;
        af[c*2]   = (short)f2bf(f0);
        af[c*2+1] = (short)f2bf(f1);
      }
      #pragma unroll
      for (int jf=0;jf<4;++jf){
        short8 bv = *(const short8*)&Vs[(jf*16+lr)*64 + kk*32 + kq];
        acc[jf] = __builtin_amdgcn_mfma_f32_16x16x32_bf16(af, bv, acc[jf], 0, 0, 0);
      }
    }
    __syncthreads();
  }
  rsum += __shfl_xor(rsum, 16, 64);
  rsum += __shfl_xor(rsum, 32, 64);
  size_t sbase = (((size_t)ch*NB + b)*NHEAD + m)*64;
  if (sub == 0) sump[sbase + irow] = rsum;
  float* cb = ctx8 + (((size_t)ch*NB + b)*NHEAD + m)*4096;
  #pragma unroll
  for (int jf=0;jf<4;++jf)
    #pragma unroll
    for (int r=0;r<4;++r){
      int i = w*16 + (l>>4)*4 + r;
      int j = jf*16 + lr;
      cb[i*64 + j] = acc[jf][r];
    }
}

// ---- W_eff: plain-sum merge of 8 chunk-partials, then fold w_out ----
__global__ __launch_bounds__(256) void k_weff(const float* __restrict__ ctx8,
                                              const float* __restrict__ sump,
                                              const float* __restrict__ wout,
                                              unsigned short* __restrict__ weff){
  __shared__ float cs[64][65];
  __shared__ float invZ[64];
  int m = blockIdx.x, b = blockIdx.y, z = blockIdx.z;
  int t = threadIdx.x, w = t>>6, l = t&63;
  const size_t chs = (size_t)NB*NHEAD*4096;
  const size_t sts = (size_t)NB*NHEAD*64;
  size_t sb = ((size_t)b*NHEAD + m)*64;
  if (t < 64){
    float Z = 0.f;
    #pragma unroll
    for (int c=0;c<8;++c) Z += sump[sb + c*sts + t];
    invZ[t] = 1.f/Z;
  }
  __syncthreads();
  const float* cb = ctx8 + ((size_t)b*NHEAD + m)*4096;
  for (int idx=t; idx<4096; idx+=256){
    int i = idx>>6;
    float v = 0.f;
    #pragma unroll
    for (int c=0;c<8;++c) v += cb[idx + c*chs];
    cs[i][idx&63] = v * invZ[i];
  }
  __syncthreads();
  for (int oo=0;oo<32;++oo){
    int o = z*128 + w*32 + oo;
    float acc = 0.f;
    #pragma unroll
    for (int j=0;j<64;++j) acc += wout[(size_t)o*CDIM + m*64 + j] * cs[l][j];
    weff[((size_t)b*CDIM + o)*CDIM + m*64 + l] = f2bf(acc);
  }
}

// ---- fused final GEMM + bias + channel-LN: 512(o) x 128(n), BK=64 split-half,
//      XCD b-locality swizzle (r15 proven). ----
__global__ __launch_bounds__(512) void k_out_ln(const unsigned short* __restrict__ Weff,
                                                const unsigned short* __restrict__ QT,
                                                const float* __restrict__ bias,
                                                const float* __restrict__ g,
                                                float* __restrict__ out){
  __shared__ char pool[81920];
  unsigned short* As0 = (unsigned short*)pool;             // 512x32
  unsigned short* As1 = (unsigned short*)(pool + 32768);   // 512x32
  unsigned short* Bs0 = (unsigned short*)(pool + 65536);   // 128x32
  unsigned short* Bs1 = (unsigned short*)(pool + 73728);   // 128x32
  int fid = blockIdx.x + 32*blockIdx.y;
  int xcd = fid & 7, j = fid >> 3;
  int b  = xcd*2 + (j & 1);
  int n0 = (j >> 1) * 128;
  const unsigned short* Ab = Weff + (size_t)b*CDIM*CDIM;
  const unsigned short* Bb = QT + ((size_t)b*NSEQ + n0)*CDIM;
  int t = threadIdx.x, w = t>>6, l = t&63;
  int lr = l&15, kq = (l>>4)*8;
  f32x4 acc[4][8];
  #pragma unroll
  for (int mi=0;mi<4;mi++)
    #pragma unroll
    for (int ni=0;ni<8;ni++) acc[mi][ni] = (f32x4){0.f,0.f,0.f,0.f};
  for (int k0=0;k0<CDIM;k0+=64){
    #pragma unroll
    for (int it=0;it<4;++it){
      int chunk = it*512 + t;
      int row = chunk>>2, kc = (chunk&3)*8;
      gld_lds16(Ab + (size_t)row*CDIM + k0 + kc,      (char*)As0 + (size_t)chunk*16);
      gld_lds16(Ab + (size_t)row*CDIM + k0 + 32 + kc, (char*)As1 + (size_t)chunk*16);
    }
    {
      int row = t>>2, kc = (t&3)*8;
      gld_lds16(Bb + (size_t)row*CDIM + k0 + kc,      (char*)Bs0 + (size_t)t*16);
      gld_lds16(Bb + (size_t)row*CDIM + k0 + 32 + kc, (char*)Bs1 + (size_t)t*16);
    }
    __syncthreads();
    #pragma unroll
    for (int h=0;h<2;++h){
      const unsigned short* Ash = h ? As1 : As0;
      const unsigned short* Bsh = h ? Bs1 : Bs0;
      short8 af[4], bfv[8];
      #pragma unroll
      for (int mi=0;mi<4;mi++) af[mi]  = *(const short8*)&Ash[(w*64 + mi*16 + lr)*32 + kq];
      #pragma unroll
      for (int ni=0;ni<8;ni++) bfv[ni] = *(const short8*)&Bsh[(ni*16 + lr)*32 + kq];
      #pragma unroll
      for (int mi=0;mi<4;mi++)
        #pragma unroll
        for (int ni=0;ni<8;ni++)
          acc[mi][ni] = __builtin_amdgcn_mfma_f32_16x16x32_bf16(af[mi], bfv[ni], acc[mi][ni], 0, 0, 0);
    }
    __syncthreads();
  }
  float* lnS  = (float*)(pool + 65536);
  float* lnS2 = lnS + 128;
  if (t < 128){ lnS[t] = 0.f; lnS2[t] = 0.f; }
  __syncthreads();
  float ps[8], ps2[8];
  #pragma unroll
  for (int ni=0;ni<8;ni++){ ps[ni]=0.f; ps2[ni]=0.f; }
  #pragma unroll
  for (int mi=0;mi<4;mi++)
    #pragma unroll
    for (int r=0;r<4;r++){
      int row = w*64 + mi*16 + (l>>4)*4 + r;
      float bb = bias[row];
      #pragma unroll
      for (int ni=0;ni<8;ni++){
        float v = acc[mi][ni][r] + bb;
        acc[mi][ni][r] = v;
        ps[ni] += v; ps2[ni] += v*v;
      }
    }
  #pragma unroll
  for (int ni=0;ni<8;ni++){
    ps[ni]  += __shfl_xor(ps[ni], 16, 64);  ps[ni]  += __shfl_xor(ps[ni], 32, 64);
    ps2[ni] += __shfl_xor(ps2[ni], 16, 64); ps2[ni] += __shfl_xor(ps2[ni], 32, 64);
  }
  if ((l>>4) == 0){
    #pragma unroll
    for (int ni=0;ni<8;ni++){
      atomicAdd(&lnS[ni*16+lr],  ps[ni]);
      atomicAdd(&lnS2[ni*16+lr], ps2[ni]);
    }
  }
  __syncthreads();
  if (t < 128){
    float mean = lnS[t]*(1.f/512.f);
    float var  = lnS2[t]*(1.f/512.f) - mean*mean;
    lnS[t] = mean; lnS2[t] = rsqrtf(var + 1e-5f);
  }
  __syncthreads();
  float* ob = out + (size_t)b*CDIM*NSEQ + n0;
  #pragma unroll
  for (int ni=0;ni<8;ni++){
    int col = ni*16 + lr;
    float mean = lnS[col], rstd = lnS2[col];
    #pragma unroll
    for (int mi=0;mi<4;mi++)
      #pragma unroll
      for (int r=0;r<4;r++){
        int row = w*64 + mi*16 + (l>>4)*4 + r;
        ob[(size_t)row*NSEQ + col] = (acc[mi][ni][r] - mean)*rstd*g[row];
      }
  }
}

extern "C" void kernel_launch(void* const* d_in, const int* in_sizes, int n_in,
                              void* d_out, int out_size, void* d_ws, size_t ws_size,
                              hipStream_t stream){
  const float* x     = (const float*)d_in[0];
  const float* w_qkv = (const float*)d_in[1];
  const float* w_out = (const float*)d_in[2];
  const float* b_out = (const float*)d_in[3];
  const float* g_out = (const float*)d_in[4];
  float* out = (float*)d_out;
  char* ws = (char*)d_ws;

  size_t off = 0;
  unsigned short* wq_bf = (unsigned short*)(ws + off); off += (size_t)O3*CDIM*2;          // 1.5 MB
  char* xT_region = ws + off;                          off += (size_t)NB*NSEQ*CDIM*2;     // 67 MB
  unsigned short* qkv_kv = (unsigned short*)(ws + off); off += (size_t)NB*1024*NSEQ*2;    // 134 MB
  unsigned short* qsmT   = (unsigned short*)(ws + off); off += (size_t)NB*NSEQ*CDIM*2;    // 67 MB
  if (off > ws_size) return;
  unsigned short* xT = (unsigned short*)xT_region;
  // aliases into xT region (xT dead after both GEMMs):
  float* sump = (float*)(xT_region);                        // 256 KB (8 chunks)
  float* ctx8 = (float*)(xT_region + (1<<20));              // 16.8 MB (8 chunks)
  unsigned short* weff = (unsigned short*)(xT_region + (20<<20)); // 8.4 MB

  k_transpose_conv<<<8960, 256, 0, stream>>>(x, w_qkv, xT, wq_bf);
  k_gemm_kv    <<<4096, 256, 0, stream>>>(wq_bf + (size_t)512*CDIM, xT, qkv_kv);
  k_gemm_q     <<<2048, 256, 0, stream>>>(wq_bf, xT, qsmT);
  k_context    <<<dim3(NHEAD, NB, 8), 256, 0, stream>>>(qkv_kv, ctx8, sump);
  k_weff       <<<dim3(NHEAD, NB, 4), 256, 0, stream>>>(ctx8, sump, w_out, weff);
  k_out_ln     <<<dim3(NSEQ/128, NB), 512, 0, stream>>>(weff, qsmT, b_out, g_out, out);
}

// Round 17
// 353.592 us; speedup vs baseline: 1.1326x; 1.0252x over previous
//
#include <hip/hip_runtime.h>

#define NB 16
#define CDIM 512
#define NHEAD 8
#define DHEAD 64
#define NSEQ 4096
#define O3 1536

typedef __attribute__((ext_vector_type(8))) short short8;
typedef __attribute__((ext_vector_type(4))) float f32x4;
typedef __attribute__((ext_vector_type(4))) unsigned u32x4;
typedef __attribute__((ext_vector_type(2))) unsigned u32x2;
typedef __attribute__((ext_vector_type(4))) float fvec4;

__device__ __forceinline__ float bf2f(unsigned short u){
  union { unsigned u; float f; } v; v.u = ((unsigned)u) << 16; return v.f;
}
__device__ __forceinline__ unsigned short f2bf(float f){
  union { float f; unsigned u; } v; v.f = f;
  unsigned r = v.u + 0x7fffu + ((v.u >> 16) & 1u);
  return (unsigned short)(r >> 16);
}
__device__ __forceinline__ unsigned pack2(float a, float b){
  return (unsigned)f2bf(a) | ((unsigned)f2bf(b) << 16);
}
__device__ __forceinline__ void gld_lds16(const void* g, void* l){
  __builtin_amdgcn_global_load_lds(
      (const __attribute__((address_space(1))) unsigned*)g,
      (__attribute__((address_space(3))) unsigned*)l, 16, 0, 0);
}

// ---- merged: x transpose (fid<8192) + w_qkv f32->bf16 (fid>=8192) ----
__global__ __launch_bounds__(256) void k_transpose_conv(const float* __restrict__ x,
                                                        const float* __restrict__ wq,
                                                        unsigned short* __restrict__ xT,
                                                        unsigned short* __restrict__ wq_bf){
  __shared__ unsigned short tile[64][65];
  int fid = blockIdx.x;
  int t = threadIdx.x;
  if (fid >= 8192){
    int i = ((fid - 8192)*256 + t)*4;
    fvec4 v = *(const fvec4*)(wq + i);
    u32x2 p; p[0] = pack2(v[0], v[1]); p[1] = pack2(v[2], v[3]);
    *(u32x2*)(wq_bf + i) = p;
    return;
  }
  int b = fid >> 9, c0 = ((fid >> 6) & 7)*64, n0 = (fid & 63)*64;
  const float* xb = x + ((size_t)b*CDIM + c0)*NSEQ + n0;
  #pragma unroll
  for (int i=0;i<4;i++){
    int idx = t + i*256;
    int r = idx>>4, c4 = (idx&15)*4;
    fvec4 v = *(const fvec4*)(xb + (size_t)r*NSEQ + c4);
    tile[r][c4]   = f2bf(v[0]);
    tile[r][c4+1] = f2bf(v[1]);
    tile[r][c4+2] = f2bf(v[2]);
    tile[r][c4+3] = f2bf(v[3]);
  }
  __syncthreads();
  unsigned short* ob = xT + ((size_t)b*NSEQ + n0)*CDIM + c0;
  #pragma unroll
  for (int i=0;i<2;i++){
    int chunk = t + i*256;
    int r = chunk>>3, c8 = (chunk&7)*8;
    u32x4 p;
    #pragma unroll
    for (int k=0;k<4;k++)
      p[k] = (unsigned)tile[c8+2*k][r] | ((unsigned)tile[c8+2*k+1][r] << 16);
    *(u32x4*)(ob + (size_t)r*CDIM + c8) = p;
  }
}

// ---- k/v GEMM: BK=64 via two split 128x32 half-tiles (r6/r14 proven body) ----
__global__ __launch_bounds__(256) void k_gemm_kv(const unsigned short* __restrict__ A,
                                                 const unsigned short* __restrict__ Bt,
                                                 unsigned short* __restrict__ KV){
  __shared__ unsigned short As[2][128*32];   // 16 KB
  __shared__ unsigned short Bs[2][128*32];   // 16 KB
  int b = blockIdx.z;
  int n0 = blockIdx.x*128, o0 = blockIdx.y*128;
  const unsigned short* Bb = Bt + (size_t)b*NSEQ*CDIM;
  unsigned short* Cb = KV + (size_t)b*1024*NSEQ;
  int t = threadIdx.x, w = t>>6, l = t&63;
  int lr = l&15, kq = (l>>4)*8;
  int wr = (w>>1)*64, wc = (w&1)*64;
  f32x4 acc[4][4];
  #pragma unroll
  for (int mi=0;mi<4;mi++)
    #pragma unroll
    for (int ni=0;ni<4;ni++) acc[mi][ni] = (f32x4){0.f,0.f,0.f,0.f};
  for (int k0=0;k0<CDIM;k0+=64){
    #pragma unroll
    for (int h=0;h<2;++h){
      #pragma unroll
      for (int it=0;it<2;++it){
        int chunk = it*256 + t;
        int row = chunk>>2, kc = (chunk&3)*8;
        gld_lds16(A  + (size_t)(o0+row)*CDIM + k0 + h*32 + kc, (char*)As[h] + (size_t)chunk*16);
        gld_lds16(Bb + (size_t)(n0+row)*CDIM + k0 + h*32 + kc, (char*)Bs[h] + (size_t)chunk*16);
      }
    }
    __syncthreads();
    #pragma unroll
    for (int h=0;h<2;++h){
      short8 af[4], bfv[4];
      #pragma unroll
      for (int mi=0;mi<4;mi++) af[mi]  = *(const short8*)&As[h][(wr + mi*16 + lr)*32 + kq];
      #pragma unroll
      for (int ni=0;ni<4;ni++) bfv[ni] = *(const short8*)&Bs[h][(wc + ni*16 + lr)*32 + kq];
      #pragma unroll
      for (int mi=0;mi<4;mi++)
        #pragma unroll
        for (int ni=0;ni<4;ni++)
          acc[mi][ni] = __builtin_amdgcn_mfma_f32_16x16x32_bf16(af[mi], bfv[ni], acc[mi][ni], 0, 0, 0);
    }
    __syncthreads();
  }
  #pragma unroll
  for (int mi=0;mi<4;mi++)
    #pragma unroll
    for (int ni=0;ni<4;ni++)
      #pragma unroll
      for (int r=0;r<4;r++){
        int row = o0 + wr + mi*16 + (l>>4)*4 + r;
        int col = n0 + wc + ni*16 + lr;
        Cb[(size_t)row*NSEQ + col] = f2bf(acc[mi][ni][r]);
      }
}

// ---- q GEMM (BK=64 split halves) + in-register head-softmax -> qsmT ----
#define TS 136
__global__ __launch_bounds__(256) void k_gemm_q(const unsigned short* __restrict__ A,
                                                const unsigned short* __restrict__ Bt,
                                                unsigned short* __restrict__ qsmT){
  __shared__ unsigned short smem[128*128];   // 32 KB: 4x 128x32 halves; epilogue tile aliases
  int b = blockIdx.z;
  int n0 = blockIdx.x*128, o0 = blockIdx.y*128;
  const unsigned short* Bb = Bt + (size_t)b*NSEQ*CDIM;
  int t = threadIdx.x, w = t>>6, l = t&63;
  int lr = l&15, kq = (l>>4)*8;
  int wr = (w>>1)*64, wc = (w&1)*64;
  f32x4 acc[4][4];
  #pragma unroll
  for (int mi=0;mi<4;mi++)
    #pragma unroll
    for (int ni=0;ni<4;ni++) acc[mi][ni] = (f32x4){0.f,0.f,0.f,0.f};
  for (int k0=0;k0<CDIM;k0+=64){
    #pragma unroll
    for (int h=0;h<2;++h){
      unsigned short* Ash = smem + h*4096;
      unsigned short* Bsh = smem + 8192 + h*4096;
      #pragma unroll
      for (int it=0;it<2;++it){
        int chunk = it*256 + t;
        int row = chunk>>2, kc = (chunk&3)*8;
        gld_lds16(A  + (size_t)(o0+row)*CDIM + k0 + h*32 + kc, (char*)Ash + (size_t)chunk*16);
        gld_lds16(Bb + (size_t)(n0+row)*CDIM + k0 + h*32 + kc, (char*)Bsh + (size_t)chunk*16);
      }
    }
    __syncthreads();
    #pragma unroll
    for (int h=0;h<2;++h){
      const unsigned short* Ash = smem + h*4096;
      const unsigned short* Bsh = smem + 8192 + h*4096;
      short8 af[4], bfv[4];
      #pragma unroll
      for (int mi=0;mi<4;mi++) af[mi]  = *(const short8*)&Ash[(wr + mi*16 + lr)*32 + kq];
      #pragma unroll
      for (int ni=0;ni<4;ni++) bfv[ni] = *(const short8*)&Bsh[(wc + ni*16 + lr)*32 + kq];
      #pragma unroll
      for (int mi=0;mi<4;mi++)
        #pragma unroll
        for (int ni=0;ni<4;ni++)
          acc[mi][ni] = __builtin_amdgcn_mfma_f32_16x16x32_bf16(af[mi], bfv[ni], acc[mi][ni], 0, 0, 0);
    }
    __syncthreads();
  }
  unsigned pk[4][4][2];
  #pragma unroll
  for (int ni=0;ni<4;ni++){
    float mx = -1e30f;
    #pragma unroll
    for (int mi=0;mi<4;mi++)
      #pragma unroll
      for (int r=0;r<4;r++) mx = fmaxf(mx, acc[mi][ni][r]);
    mx = fmaxf(mx, __shfl_xor(mx, 16, 64));
    mx = fmaxf(mx, __shfl_xor(mx, 32, 64));
    float s = 0.f;
    #pragma unroll
    for (int mi=0;mi<4;mi++)
      #pragma unroll
      for (int r=0;r<4;r++){
        float p = __expf(acc[mi][ni][r] - mx);
        acc[mi][ni][r] = p; s += p;
      }
    s += __shfl_xor(s, 16, 64);
    s += __shfl_xor(s, 32, 64);
    float inv = 0.125f / s;
    #pragma unroll
    for (int mi=0;mi<4;mi++){
      pk[mi][ni][0] = pack2(acc[mi][ni][0]*inv, acc[mi][ni][1]*inv);
      pk[mi][ni][1] = pack2(acc[mi][ni][2]*inv, acc[mi][ni][3]*inv);
    }
  }
  #pragma unroll
  for (int ck=0;ck<2;++ck){
    if ((w&1) == ck){
      #pragma unroll
      for (int mi=0;mi<4;mi++)
        #pragma unroll
        for (int ni=0;ni<4;ni++){
          int idx = (ni*16 + lr)*TS + wr + mi*16 + (l>>4)*4;
          u32x2 p; p[0] = pk[mi][ni][0]; p[1] = pk[mi][ni][1];
          *(u32x2*)&smem[idx] = p;
        }
    }
    __syncthreads();
    int col = t>>2, rs = (t&3)*32;
    unsigned short* dst = qsmT + ((size_t)b*NSEQ + n0 + ck*64 + col)*CDIM + o0 + rs;
    #pragma unroll
    for (int j=0;j<4;++j)
      *(u32x4*)(dst + j*8) = *(const u32x4*)&smem[col*TS + rs + j*8];
    __syncthreads();
  }
}

// ---- partial context over n-chunk (512 cols), NO max pass: exp(k) directly ----
__global__ __launch_bounds__(256) void k_context(const unsigned short* __restrict__ KV,
                                                 float* __restrict__ ctx8,
                                                 float* __restrict__ sump){
  __shared__ unsigned short Vs[64*64];
  int m = blockIdx.x, b = blockIdx.y, ch = blockIdx.z;
  int t = threadIdx.x, w = t>>6, l = t&63;
  int lr = l&15, kq = (l>>4)*8;
  const unsigned short* kbase = KV + ((size_t)b*1024 + m*64)*NSEQ;
  const unsigned short* vbase = KV + ((size_t)b*1024 + 512 + m*64)*NSEQ;
  int irow = w*16 + lr;
  int sub = l>>4;
  int nbeg = ch*512;
  float rsum = 0.f;
  f32x4 acc[4];
  #pragma unroll
  for (int jf=0;jf<4;++jf) acc[jf] = (f32x4){0.f,0.f,0.f,0.f};
  for (int n0=nbeg;n0<nbeg+512;n0+=64){
    #pragma unroll
    for (int it=0;it<2;++it){
      int chunk = it*256 + t;
      int row = chunk>>3, kc = (chunk&7)*8;
      gld_lds16(vbase + (size_t)row*NSEQ + n0 + kc, (char*)Vs + (size_t)chunk*16);
    }
    __syncthreads();
    #pragma unroll
    for (int kk=0;kk<2;++kk){
      u32x4 kraw = *(const u32x4*)(kbase + (size_t)irow*NSEQ + n0 + kk*32 + kq);
      short8 af;
      #pragma unroll
      for (int c=0;c<4;++c){
        unsigned u = kraw[c];
        float f0 = __expf(bf2f((unsigned short)u));
        float f1 = __expf(bf2f((unsigned short)(u>>16)));
        rsum += f0 + f1;
        af[c*2]   = (short)f2bf(f0);
        af[c*2+1] = (short)f2bf(f1);
      }
      #pragma unroll
      for (int jf=0;jf<4;++jf){
        short8 bv = *(const short8*)&Vs[(jf*16+lr)*64 + kk*32 + kq];
        acc[jf] = __builtin_amdgcn_mfma_f32_16x16x32_bf16(af, bv, acc[jf], 0, 0, 0);
      }
    }
    __syncthreads();
  }
  rsum += __shfl_xor(rsum, 16, 64);
  rsum += __shfl_xor(rsum, 32, 64);
  size_t sbase = (((size_t)ch*NB + b)*NHEAD + m)*64;
  if (sub == 0) sump[sbase + irow] = rsum;
  float* cb = ctx8 + (((size_t)ch*NB + b)*NHEAD + m)*4096;
  #pragma unroll
  for (int jf=0;jf<4;++jf)
    #pragma unroll
    for (int r=0;r<4;++r){
      int i = w*16 + (l>>4)*4 + r;
      int j = jf*16 + lr;
      cb[i*64 + j] = acc[jf][r];
    }
}

// ---- W_eff: plain-sum merge of 8 chunk-partials, then fold w_out ----
__global__ __launch_bounds__(256) void k_weff(const float* __restrict__ ctx8,
                                              const float* __restrict__ sump,
                                              const float* __restrict__ wout,
                                              unsigned short* __restrict__ weff){
  __shared__ float cs[64][65];
  __shared__ float invZ[64];
  int m = blockIdx.x, b = blockIdx.y, z = blockIdx.z;
  int t = threadIdx.x, w = t>>6, l = t&63;
  const size_t chs = (size_t)NB*NHEAD*4096;
  const size_t sts = (size_t)NB*NHEAD*64;
  size_t sb = ((size_t)b*NHEAD + m)*64;
  if (t < 64){
    float Z = 0.f;
    #pragma unroll
    for (int c=0;c<8;++c) Z += sump[sb + c*sts + t];
    invZ[t] = 1.f/Z;
  }
  __syncthreads();
  const float* cb = ctx8 + ((size_t)b*NHEAD + m)*4096;
  for (int idx=t; idx<4096; idx+=256){
    int i = idx>>6;
    float v = 0.f;
    #pragma unroll
    for (int c=0;c<8;++c) v += cb[idx + c*chs];
    cs[i][idx&63] = v * invZ[i];
  }
  __syncthreads();
  for (int oo=0;oo<32;++oo){
    int o = z*128 + w*32 + oo;
    float acc = 0.f;
    #pragma unroll
    for (int j=0;j<64;++j) acc += wout[(size_t)o*CDIM + m*64 + j] * cs[l][j];
    weff[((size_t)b*CDIM + o)*CDIM + m*64 + l] = f2bf(acc);
  }
}

// ---- fused final GEMM + bias + channel-LN: 512(o) x 128(n), BK=64 split-half,
//      XCD b-locality swizzle (r15 proven). ----
__global__ __launch_bounds__(512) void k_out_ln(const unsigned short* __restrict__ Weff,
                                                const unsigned short* __restrict__ QT,
                                                const float* __restrict__ bias,
                                                const float* __restrict__ g,
                                                float* __restrict__ out){
  __shared__ char pool[81920];
  unsigned short* As0 = (unsigned short*)pool;             // 512x32
  unsigned short* As1 = (unsigned short*)(pool + 32768);   // 512x32
  unsigned short* Bs0 = (unsigned short*)(pool + 65536);   // 128x32
  unsigned short* Bs1 = (unsigned short*)(pool + 73728);   // 128x32
  int fid = blockIdx.x + 32*blockIdx.y;
  int xcd = fid & 7, j = fid >> 3;
  int b  = xcd*2 + (j & 1);
  int n0 = (j >> 1) * 128;
  const unsigned short* Ab = Weff + (size_t)b*CDIM*CDIM;
  const unsigned short* Bb = QT + ((size_t)b*NSEQ + n0)*CDIM;
  int t = threadIdx.x, w = t>>6, l = t&63;
  int lr = l&15, kq = (l>>4)*8;
  f32x4 acc[4][8];
  #pragma unroll
  for (int mi=0;mi<4;mi++)
    #pragma unroll
    for (int ni=0;ni<8;ni++) acc[mi][ni] = (f32x4){0.f,0.f,0.f,0.f};
  for (int k0=0;k0<CDIM;k0+=64){
    #pragma unroll
    for (int it=0;it<4;++it){
      int chunk = it*512 + t;
      int row = chunk>>2, kc = (chunk&3)*8;
      gld_lds16(Ab + (size_t)row*CDIM + k0 + kc,      (char*)As0 + (size_t)chunk*16);
      gld_lds16(Ab + (size_t)row*CDIM + k0 + 32 + kc, (char*)As1 + (size_t)chunk*16);
    }
    {
      int row = t>>2, kc = (t&3)*8;
      gld_lds16(Bb + (size_t)row*CDIM + k0 + kc,      (char*)Bs0 + (size_t)t*16);
      gld_lds16(Bb + (size_t)row*CDIM + k0 + 32 + kc, (char*)Bs1 + (size_t)t*16);
    }
    __syncthreads();
    #pragma unroll
    for (int h=0;h<2;++h){
      const unsigned short* Ash = h ? As1 : As0;
      const unsigned short* Bsh = h ? Bs1 : Bs0;
      short8 af[4], bfv[8];
      #pragma unroll
      for (int mi=0;mi<4;mi++) af[mi]  = *(const short8*)&Ash[(w*64 + mi*16 + lr)*32 + kq];
      #pragma unroll
      for (int ni=0;ni<8;ni++) bfv[ni] = *(const short8*)&Bsh[(ni*16 + lr)*32 + kq];
      #pragma unroll
      for (int mi=0;mi<4;mi++)
        #pragma unroll
        for (int ni=0;ni<8;ni++)
          acc[mi][ni] = __builtin_amdgcn_mfma_f32_16x16x32_bf16(af[mi], bfv[ni], acc[mi][ni], 0, 0, 0);
    }
    __syncthreads();
  }
  float* lnS  = (float*)(pool + 65536);
  float* lnS2 = lnS + 128;
  if (t < 128){ lnS[t] = 0.f; lnS2[t] = 0.f; }
  __syncthreads();
  float ps[8], ps2[8];
  #pragma unroll
  for (int ni=0;ni<8;ni++){ ps[ni]=0.f; ps2[ni]=0.f; }
  #pragma unroll
  for (int mi=0;mi<4;mi++)
    #pragma unroll
    for (int r=0;r<4;r++){
      int row = w*64 + mi*16 + (l>>4)*4 + r;
      float bb = bias[row];
      #pragma unroll
      for (int ni=0;ni<8;ni++){
        float v = acc[mi][ni][r] + bb;
        acc[mi][ni][r] = v;
        ps[ni] += v; ps2[ni] += v*v;
      }
    }
  #pragma unroll
  for (int ni=0;ni<8;ni++){
    ps[ni]  += __shfl_xor(ps[ni], 16, 64);  ps[ni]  += __shfl_xor(ps[ni], 32, 64);
    ps2[ni] += __shfl_xor(ps2[ni], 16, 64); ps2[ni] += __shfl_xor(ps2[ni], 32, 64);
  }
  if ((l>>4) == 0){
    #pragma unroll
    for (int ni=0;ni<8;ni++){
      atomicAdd(&lnS[ni*16+lr],  ps[ni]);
      atomicAdd(&lnS2[ni*16+lr], ps2[ni]);
    }
  }
  __syncthreads();
  if (t < 128){
    float mean = lnS[t]*(1.f/512.f);
    float var  = lnS2[t]*(1.f/512.f) - mean*mean;
    lnS[t] = mean; lnS2[t] = rsqrtf(var + 1e-5f);
  }
  __syncthreads();
  float* ob = out + (size_t)b*CDIM*NSEQ + n0;
  #pragma unroll
  for (int ni=0;ni<8;ni++){
    int col = ni*16 + lr;
    float mean = lnS[col], rstd = lnS2[col];
    #pragma unroll
    for (int mi=0;mi<4;mi++)
      #pragma unroll
      for (int r=0;r<4;r++){
        int row = w*64 + mi*16 + (l>>4)*4 + r;
        ob[(size_t)row*NSEQ + col] = (acc[mi][ni][r] - mean)*rstd*g[row];
      }
  }
}

extern "C" void kernel_launch(void* const* d_in, const int* in_sizes, int n_in,
                              void* d_out, int out_size, void* d_ws, size_t ws_size,
                              hipStream_t stream){
  const float* x     = (const float*)d_in[0];
  const float* w_qkv = (const float*)d_in[1];
  const float* w_out = (const float*)d_in[2];
  const float* b_out = (const float*)d_in[3];
  const float* g_out = (const float*)d_in[4];
  float* out = (float*)d_out;
  char* ws = (char*)d_ws;

  size_t off = 0;
  unsigned short* wq_bf = (unsigned short*)(ws + off); off += (size_t)O3*CDIM*2;          // 1.5 MB
  char* xT_region = ws + off;                          off += (size_t)NB*NSEQ*CDIM*2;     // 67 MB
  unsigned short* qkv_kv = (unsigned short*)(ws + off); off += (size_t)NB*1024*NSEQ*2;    // 134 MB
  unsigned short* qsmT   = (unsigned short*)(ws + off); off += (size_t)NB*NSEQ*CDIM*2;    // 67 MB
  if (off > ws_size) return;
  unsigned short* xT = (unsigned short*)xT_region;
  // aliases into xT region (xT dead after both GEMMs):
  float* sump = (float*)(xT_region);                        // 256 KB (8 chunks)
  float* ctx8 = (float*)(xT_region + (1<<20));              // 16.8 MB (8 chunks)
  unsigned short* weff = (unsigned short*)(xT_region + (20<<20)); // 8.4 MB

  k_transpose_conv<<<8960, 256, 0, stream>>>(x, w_qkv, xT, wq_bf);
  k_gemm_kv    <<<dim3(NSEQ/128, 8, NB), 256, 0, stream>>>(wq_bf + (size_t)512*CDIM, xT, qkv_kv);
  k_gemm_q     <<<dim3(NSEQ/128, 4, NB), 256, 0, stream>>>(wq_bf, xT, qsmT);
  k_context    <<<dim3(NHEAD, NB, 8), 256, 0, stream>>>(qkv_kv, ctx8, sump);
  k_weff       <<<dim3(NHEAD, NB, 4), 256, 0, stream>>>(ctx8, sump, w_out, weff);
  k_out_ln     <<<dim3(NSEQ/128, NB), 512, 0, stream>>>(weff, qsmT, b_out, g_out, out);
}